// Round 7
// baseline (639.360 us; speedup 1.0000x reference)
//
#include <hip/hip_runtime.h>

#define B_    4
#define T_    4096
#define D_    1024
#define H_    16
#define DH_   64
#define KTOK  2048
#define MROWS (B_*KTOK)   // 8192

typedef unsigned short u16;
typedef __attribute__((ext_vector_type(8))) short short8;
typedef __attribute__((ext_vector_type(4))) float f32x4;
typedef __attribute__((ext_vector_type(4))) unsigned int u32x4;
typedef __attribute__((ext_vector_type(2))) unsigned int u32x2;
typedef __attribute__((ext_vector_type(4))) unsigned short u16x4;

static __device__ __forceinline__ u16 f2bf(float f) {
  union { float f; unsigned int u; } a; a.f = f;
  unsigned int u = a.u;
  unsigned int r = (u + 0x7FFFu + ((u >> 16) & 1u)) >> 16;   // RNE
  return (u16)r;
}

#if defined(__has_builtin)
#if __has_builtin(__builtin_amdgcn_exp2f)
#define EXP2F(x) __builtin_amdgcn_exp2f(x)
#endif
#endif
#ifndef EXP2F
#define EXP2F(x) exp2f(x)
#endif

// fast erf-based gelu: Abramowitz-Stegun 7.1.26, |err(erf)| < 2e-7 (vs bf16 ulp ~4e-3)
static __device__ __forceinline__ float gelu_f(float v) {
  float x = fabsf(v) * 0.70710678118654752f;
  float t = __builtin_amdgcn_rcpf(1.0f + 0.3275911f * x);
  float p = t * (0.254829592f + t * (-0.284496736f + t * (1.421413741f +
            t * (-1.453152027f + t * 1.061405429f))));
  float e = EXP2F(-1.4426950408889634f * x * x);
  float er = 1.0f - p * e;                    // erf(|x|)
  er = (v < 0.0f) ? -er : er;
  return 0.5f * v * (1.0f + er);
}

// pack two fp32 -> adjacent bf16 pair (low = a), TRUNCATING (1 v_perm).
static __device__ __forceinline__ unsigned int pkbf_t(float a, float b) {
  unsigned int ua = __builtin_bit_cast(unsigned int, a);
  unsigned int ub = __builtin_bit_cast(unsigned int, b);
  return __builtin_amdgcn_perm(ub, ua, 0x07060302u);  // [ua.hi16 low, ub.hi16 high]
}

static __device__ __forceinline__ void gld_lds16(const u16* g, u16* l) {
  __builtin_amdgcn_global_load_lds((__attribute__((address_space(1))) void*)g,
                                   (__attribute__((address_space(3))) void*)l, 16, 0, 0);
}

#define WAITV(N) asm volatile("s_waitcnt vmcnt(" #N ")" ::: "memory")

// ---------------- router: logits = x @ w_router, accumulate sum(logits^2) ----------------
__global__ void __launch_bounds__(256) router_kernel(const float* __restrict__ x,
    const float* __restrict__ wr, float* __restrict__ logits, float* __restrict__ auxacc)
{
  int tid = threadIdx.x; int lane = tid & 63, wave = tid >> 6;
  int row = blockIdx.x * 4 + wave;                 // 0 .. B*T-1
  const float* xr = x + (size_t)row * D_;
  float dot = 0.f;
#pragma unroll
  for (int j = 0; j < 4; j++) {
    int c = j * 256 + lane * 4;
    f32x4 xv = *(const f32x4*)(xr + c);
    f32x4 wv = *(const f32x4*)(wr + c);
    dot += xv[0]*wv[0] + xv[1]*wv[1] + xv[2]*wv[2] + xv[3]*wv[3];
  }
#pragma unroll
  for (int d = 1; d < 64; d <<= 1) dot += __shfl_xor(dot, d);
  __shared__ float red[4];
  if (lane == 0) { logits[row] = dot; red[wave] = dot; }
  __syncthreads();
  if (tid == 0) {
    float a = red[0]*red[0] + red[1]*red[1] + red[2]*red[2] + red[3]*red[3];
    atomicAdd(auxacc, a);
  }
}

// -------- partial rank: grid (T/256, B, 16 chunks); atomicAdd partial counts into rnk ------
__global__ void __launch_bounds__(256) rankp_kernel(const float* __restrict__ logits,
    int* __restrict__ rnk)
{
  __shared__ float ll[256];
  const int b = blockIdx.y, ch = blockIdx.z;
  const int tid = threadIdx.x;
  const float* lg = logits + (size_t)b * T_;
  const int j0 = ch * 256;
  ll[tid] = lg[j0 + tid];
  __syncthreads();
  const int t = blockIdx.x * 256 + tid;
  const float my = lg[t];
  int rank = 0;
#pragma unroll 4
  for (int j = 0; j < 256; j += 4) {
    f32x4 lj = *(const f32x4*)&ll[j];
    int jg = j0 + j;
    rank += (lj[0] > my) || (lj[0] == my && (jg+0) < t);
    rank += (lj[1] > my) || (lj[1] == my && (jg+1) < t);
    rank += (lj[2] > my) || (lj[2] == my && (jg+2) < t);
    rank += (lj[3] > my) || (lj[3] == my && (jg+3) < t);
  }
  atomicAdd(&rnk[(size_t)b * T_ + t], rank);
}

// ---------------- fused: pass-through unselected OR gather+LN selected; builds idx --------
__global__ void __launch_bounds__(256) lnpass_kernel(const float* __restrict__ x,
    const int* __restrict__ rnk, const float* __restrict__ g, const float* __restrict__ bb,
    float* __restrict__ xs_out, u16* __restrict__ hout, float* __restrict__ out,
    int* __restrict__ idx, const float* __restrict__ acc, float* __restrict__ auxout)
{
  int row = blockIdx.x;            // 0 .. B*T-1
  int tid = threadIdx.x;
  if (row == 0 && tid == 0) auxout[0] = acc[0] * (0.01f / (float)(B_ * T_));
  const float* srow = x + (size_t)row * D_;
  f32x4 v = *(const f32x4*)(srow + tid * 4);
  int r = rnk[row];                // block-uniform
  if (r >= KTOK) {                 // unselected: copy x row to out
    *(f32x4*)(out + (size_t)row * D_ + tid * 4) = v;
    return;
  }
  if (tid == 0) idx[(row >> 12) * KTOK + r] = row & (T_ - 1);   // T_=4096
  size_t mrow = (size_t)(row >> 12) * KTOK + r;
  float s  = v[0] + v[1] + v[2] + v[3];
  float sq = v[0]*v[0] + v[1]*v[1] + v[2]*v[2] + v[3]*v[3];
#pragma unroll
  for (int d = 1; d < 64; d <<= 1) { s += __shfl_xor(s, d); sq += __shfl_xor(sq, d); }
  __shared__ float rs[4], rq[4];
  int lane = tid & 63, wave = tid >> 6;
  if (lane == 0) { rs[wave] = s; rq[wave] = sq; }
  __syncthreads();
  s  = rs[0] + rs[1] + rs[2] + rs[3];
  sq = rq[0] + rq[1] + rq[2] + rq[3];
  float mean = s * (1.0f / D_);
  float var  = sq * (1.0f / D_) - mean * mean;
  float rstd = rsqrtf(var + 1e-5f);
  f32x4 gg = *(const f32x4*)(g + tid * 4);
  f32x4 bv = *(const f32x4*)(bb + tid * 4);
  *(f32x4*)(xs_out + mrow * D_ + tid * 4) = v;
  u16x4 o;
#pragma unroll
  for (int j = 0; j < 4; j++) o[j] = f2bf((v[j] - mean) * rstd * gg[j] + bv[j]);
  *(u16x4*)(hout + mrow * D_ + tid * 4) = o;
}

// ---------------- LayerNorm (no gather) ----------------
__global__ void __launch_bounds__(256) ln2_kernel(const float* __restrict__ src,
    const float* __restrict__ g, const float* __restrict__ bb, u16* __restrict__ hout)
{
  int row = blockIdx.x;
  int tid = threadIdx.x;
  const float* srow = src + (size_t)row * D_;
  f32x4 v = *(const f32x4*)(srow + tid * 4);
  float s  = v[0] + v[1] + v[2] + v[3];
  float sq = v[0]*v[0] + v[1]*v[1] + v[2]*v[2] + v[3]*v[3];
#pragma unroll
  for (int d = 1; d < 64; d <<= 1) { s += __shfl_xor(s, d); sq += __shfl_xor(sq, d); }
  __shared__ float rs[4], rq[4];
  int lane = tid & 63, wave = tid >> 6;
  if (lane == 0) { rs[wave] = s; rq[wave] = sq; }
  __syncthreads();
  s  = rs[0] + rs[1] + rs[2] + rs[3];
  sq = rq[0] + rq[1] + rq[2] + rq[3];
  float mean = s * (1.0f / D_);
  float var  = sq * (1.0f / D_) - mean * mean;
  float rstd = rsqrtf(var + 1e-5f);
  f32x4 gg = *(const f32x4*)(g + tid * 4);
  f32x4 bv = *(const f32x4*)(bb + tid * 4);
  u16x4 o;
#pragma unroll
  for (int j = 0; j < 4; j++) o[j] = f2bf((v[j] - mean) * rstd * gg[j] + bv[j]);
  *(u16x4*)(hout + (size_t)row * D_ + tid * 4) = o;
}

// ---------------- fp32 -> bf16 convert, all 4 weight matrices in one dispatch ----------------
__global__ void __launch_bounds__(256) f2bf_all(const float* __restrict__ s0, const float* __restrict__ s1,
    const float* __restrict__ s2, const float* __restrict__ s3,
    u16* __restrict__ d0, u16* __restrict__ d1, u16* __restrict__ d2, u16* __restrict__ d3)
{
  const size_t c0 = (size_t)3 * D_ * D_, c1 = (size_t)4 * D_ * D_, c2 = (size_t)8 * D_ * D_;
  size_t e = (size_t)blockIdx.x * 1024 + (size_t)threadIdx.x * 4;
  const float* s; u16* d; size_t off;
  if (e < c0)      { s = s0; d = d0; off = e; }
  else if (e < c1) { s = s1; d = d1; off = e - c0; }
  else if (e < c2) { s = s2; d = d2; off = e - c1; }
  else             { s = s3; d = d3; off = e - c2; }
  f32x4 v = *(const f32x4*)(s + off);
  u16x4 o; o[0]=f2bf(v[0]); o[1]=f2bf(v[1]); o[2]=f2bf(v[2]); o[3]=f2bf(v[3]);
  *(u16x4*)(d + off) = o;
}

// ========== GEMM 128x128, BK=64, 4 row-waves, deep-prefetch schedule (round-5 proven) ======
template<int EPI>
__global__ void __launch_bounds__(256, 2) gemm_bt(
    const u16* __restrict__ A, const u16* __restrict__ W,
    const float* __restrict__ bias, float* __restrict__ xs,
    u16* __restrict__ Cb, float* __restrict__ outf,
    const int* __restrict__ idx, u16* __restrict__ vtb, int M, int N, int K)
{
  __shared__ u16 As[2][128 * 64];
  __shared__ u16 Ws[2][128 * 64];
  const int tid = threadIdx.x;
  const int lane = tid & 63, wave = tid >> 6;
  const int m16 = lane & 15, quad = (lane >> 4) & 3;

  // chunked bijective XCD swizzle (grid divisible by 8)
  const int gx = gridDim.x;
  const int id = blockIdx.y * gx + blockIdx.x;
  const int cpx = (gx * (int)gridDim.y) >> 3;
  const int tl = (id & 7) * cpx + (id >> 3);
  const int bx = tl % gx, by = tl / gx;

  const size_t arow0 = (size_t)by * 128;
  const size_t wrow0 = (size_t)bx * 128;

  // stage one [64][64] u16 piece (8KB = 512 chunks), thread t -> chunks t, 256+t
  const int trow = tid >> 3;                // 0..31
  const int tcc  = (tid ^ trow) & 7;        // swizzled source col-chunk (inverse of read XOR)
  auto stagepc = [&](const u16* g0, u16* l0) {
    gld_lds16(g0 + (size_t)trow * K + tcc * 8,        l0 + (size_t)(tid & ~63) * 8);
    gld_lds16(g0 + (size_t)(32 + trow) * K + tcc * 8, l0 + 2048 + (size_t)(tid & ~63) * 8);
  };
  auto stage_tile = [&](int u, int s) {     // FIFO: Ar0, Ar1, B0, B1
    size_t kn = (size_t)u * 64;
    stagepc(A + (arow0)      * K + kn, &As[s][0]);
    stagepc(A + (arow0 + 64) * K + kn, &As[s][64 * 64]);
    stagepc(W + (wrow0)      * K + kn, &Ws[s][0]);
    stagepc(W + (wrow0 + 64) * K + kn, &Ws[s][64 * 64]);
  };

  auto ldA = [&](short8 (&f)[2][2], const u16* h) {
#pragma unroll
    for (int mt = 0; mt < 2; mt++) {
      int rr = wave * 32 + mt * 16 + m16;
      int sw = rr & 7;
#pragma unroll
      for (int kk = 0; kk < 2; kk++)
        f[mt][kk] = *(const short8*)&h[rr * 64 + (((kk * 4 + quad) ^ sw) * 8)];
    }
  };
  auto ldB = [&](short8 (&f)[4][2], const u16* h, int half) {
#pragma unroll
    for (int nt = 0; nt < 4; nt++) {
      int rb = half * 64 + nt * 16 + m16;
      int sw = rb & 7;
#pragma unroll
      for (int kk = 0; kk < 2; kk++)
        f[nt][kk] = *(const short8*)&h[rb * 64 + (((kk * 4 + quad) ^ sw) * 8)];
    }
  };

  f32x4 acc[2][8];
#pragma unroll
  for (int mt = 0; mt < 2; mt++)
#pragma unroll
    for (int n = 0; n < 8; n++) acc[mt][n] = (f32x4)0.0f;

  stage_tile(0, 0);

  const int NT = K >> 6;
  short8 af[2][2], bf[4][2], bf2[4][2];

  for (int t = 0; t < NT; t++) {
    const int cur = t & 1;
    const bool last = (t == NT - 1);

    WAITV(2);                                  // Ar0,Ar1,B0(t) done (issued full tile ago)
    __builtin_amdgcn_s_barrier();
    __builtin_amdgcn_sched_barrier(0);
    if (!last) stage_tile(t + 1, cur ^ 1);

    // p0: cols 0-63
    ldA(af, &As[cur][0]);
    ldB(bf, &Ws[cur][0], 0);
    __builtin_amdgcn_s_setprio(1);
#pragma unroll
    for (int mt = 0; mt < 2; mt++)
#pragma unroll
      for (int nt = 0; nt < 4; nt++)
#pragma unroll
        for (int kk = 0; kk < 2; kk++)
          acc[mt][nt] = __builtin_amdgcn_mfma_f32_16x16x32_bf16(af[mt][kk], bf[nt][kk], acc[mt][nt], 0, 0, 0);
    __builtin_amdgcn_s_setprio(0);

    if (last) { WAITV(0); } else { WAITV(8); } // B1(t) done; t+1's 8 loads stay in flight
    __builtin_amdgcn_s_barrier();
    __builtin_amdgcn_sched_barrier(0);

    // p1: cols 64-127 (barrier-free drift region)
    ldB(bf2, &Ws[cur][0], 1);
    __builtin_amdgcn_s_setprio(1);
#pragma unroll
    for (int mt = 0; mt < 2; mt++)
#pragma unroll
      for (int nt = 0; nt < 4; nt++)
#pragma unroll
        for (int kk = 0; kk < 2; kk++)
          acc[mt][4 + nt] = __builtin_amdgcn_mfma_f32_16x16x32_bf16(af[mt][kk], bf2[nt][kk], acc[mt][4 + nt], 0, 0, 0);
    __builtin_amdgcn_s_setprio(0);
  }

  // ---- epilogue ----
#pragma unroll
  for (int half = 0; half < 2; half++) {
#pragma unroll
    for (int mt = 0; mt < 2; mt++) {
#pragma unroll
      for (int nt = 0; nt < 4; nt++) {
        f32x4 a = acc[mt][half * 4 + nt];
        size_t col = wrow0 + half * 64 + nt * 16 + m16;
        float bvv = bias[col];
        size_t rowb = arow0 + wave * 32 + mt * 16 + quad * 4;
        if (EPI == 0) {
          if ((int)col < 2 * D_) {
            float sc = ((int)col < D_) ? 0.18033688f : 1.0f;  // fold 1/sqrt(dh)*log2(e) into Q
#pragma unroll
            for (int r = 0; r < 4; r++)
              Cb[(rowb + r) * (size_t)N + col] = f2bf((a[r] + bvv) * sc);
          } else {
            int hdh = (int)col - 2 * D_;
            int bb2 = (int)(rowb >> 11);
            int tok = (int)(rowb & (KTOK - 1));
            u16x4 o;
#pragma unroll
            for (int r = 0; r < 4; r++) o[r] = f2bf(a[r] + bvv);
            *(u16x4*)&vtb[(((size_t)(bb2 * H_) + (hdh >> 6)) * 64 + (hdh & 63)) * KTOK + tok] = o;
          }
        } else if (EPI == 1) {
#pragma unroll
          for (int r = 0; r < 4; r++) {
            size_t o = (rowb + r) * (size_t)N + col;
            xs[o] = xs[o] + (a[r] + bvv);
          }
        } else {
#pragma unroll
          for (int r = 0; r < 4; r++) {
            size_t row = rowb + r;
            int b = (int)(row >> 11);
            int i = (int)(row & (KTOK - 1));
            int t = idx[b * KTOK + i];
            float vv = xs[row * (size_t)D_ + col] + (a[r] + bvv);
            outf[((size_t)b * T_ + t) * D_ + col] = vv;
          }
        }
      }
    }
  }
}

// ================= FF1 GEMM: 256x256, BK=64, 512 threads, deep-prefetch schedule ===========
__global__ void __launch_bounds__(512, 1) gemm_ff1(
    const u16* __restrict__ A, const u16* __restrict__ W,
    const float* __restrict__ bias, u16* __restrict__ Cb, int M, int N, int K)
{
  __shared__ u16 Asm[2][2][128 * 64];
  __shared__ u16 Bsm[2][2][128 * 64];

  const int tid = threadIdx.x;
  const int lane = tid & 63;
  const int w = tid >> 6;                  // wave 0..7
  const int m16 = lane & 15, quad = (lane >> 4) & 3;
  const int rowA = (w >> 2) * 64;          // within A-half
  const int rowB = (w & 3) * 32;           // within B-half

  const int gx = gridDim.x;
  const int id = blockIdx.y * gx + blockIdx.x;
  const int cpx = (gx * (int)gridDim.y) >> 3;
  const int tl = (id & 7) * cpx + (id >> 3);
  const int bx = tl % gx, by = tl / gx;

  const int arow0 = by * 256;
  const int wcol0 = bx * 256;

  const int th8 = tid >> 3;
  const int ccs = (tid ^ th8) & 7;
  auto stage = [&](const u16* g0, u16* l0) {       // one 128x64 half-tile (16KB), 2 loads/thread
    gld_lds16(g0 + (size_t)th8 * K + ccs * 8,        l0 + (size_t)(tid & ~63) * 8);
    gld_lds16(g0 + (size_t)(64 + th8) * K + ccs * 8, l0 + 4096 + (size_t)(tid & ~63) * 8);
  };
  auto stage_tile = [&](int u, int s) {            // FIFO order: A0, B0, A1, B1
    size_t kn = (size_t)u * 64;
    stage(A + (size_t)arow0 * K + kn,         &Asm[s][0][0]);
    stage(W + (size_t)wcol0 * K + kn,         &Bsm[s][0][0]);
    stage(A + (size_t)(arow0 + 128) * K + kn, &Asm[s][1][0]);
    stage(W + (size_t)(wcol0 + 128) * K + kn, &Bsm[s][1][0]);
  };

  auto ldA = [&](short8 (&f)[4][2], const u16* h) {
#pragma unroll
    for (int mt = 0; mt < 4; mt++) {
      int rr = rowA + mt * 16 + m16;
      int sw = rr & 7;
#pragma unroll
      for (int kk = 0; kk < 2; kk++)
        f[mt][kk] = *(const short8*)&h[rr * 64 + (((kk * 4 + quad) ^ sw) * 8)];
    }
  };
  auto ldB = [&](short8 (&f)[2][2], const u16* h) {
#pragma unroll
    for (int nt = 0; nt < 2; nt++) {
      int rb = rowB + nt * 16 + m16;
      int sw = rb & 7;
#pragma unroll
      for (int kk = 0; kk < 2; kk++)
        f[nt][kk] = *(const short8*)&h[rb * 64 + (((kk * 4 + quad) ^ sw) * 8)];
    }
  };

  f32x4 acc[4][4][2];
#pragma unroll
  for (int q = 0; q < 4; q++)
#pragma unroll
    for (int mt = 0; mt < 4; mt++)
#pragma unroll
      for (int nt = 0; nt < 2; nt++) acc[q][mt][nt] = (f32x4)0.0f;

#define MMQ(QD, FA, FB) do { \
  __builtin_amdgcn_s_setprio(1); \
  _Pragma("unroll") for (int mt = 0; mt < 4; mt++) \
  _Pragma("unroll") for (int nt = 0; nt < 2; nt++) \
  _Pragma("unroll") for (int kk = 0; kk < 2; kk++) \
    acc[QD][mt][nt] = __builtin_amdgcn_mfma_f32_16x16x32_bf16(FA[mt][kk], FB[nt][kk], acc[QD][mt][nt], 0, 0, 0); \
  __builtin_amdgcn_s_setprio(0); } while (0)

  stage_tile(0, 0);

  const int NT = K >> 6;
  short8 af[4][2], af2[4][2], bf[2][2], bf2[2][2];

  for (int t = 0; t < NT; t++) {
    const int cur = t & 1;
    const bool last = (t == NT - 1);

    WAITV(4);                                   // A0,B0(t) done; A1,B1(t) may be in flight
    __builtin_amdgcn_s_barrier();
    __builtin_amdgcn_sched_barrier(0);
    if (!last) stage_tile(t + 1, cur ^ 1);      // 8 loads; slots freed by this barrier

    // p0: (A0,B0)
    ldA(af, &Asm[cur][0][0]);
    ldB(bf, &Bsm[cur][0][0]);
    MMQ(0, af, bf);

    if (last) { WAITV(0); } else { WAITV(8); }  // A1,B1(t) done; t+1's 8 loads in flight
    __builtin_amdgcn_s_barrier();
    __builtin_amdgcn_sched_barrier(0);

    // p1..p3: barrier-free drift region
    ldB(bf2, &Bsm[cur][1][0]);
    MMQ(1, af, bf2);
    ldA(af2, &Asm[cur][1][0]);
    MMQ(2, af2, bf);
    MMQ(3, af2, bf2);
  }
#undef MMQ

  // ---- epilogue: gelu(bf16) ----
#pragma unroll
  for (int qd = 0; qd < 4; qd++) {
    const int ha = qd >> 1, hb = qd & 1;
#pragma unroll
    for (int mt = 0; mt < 4; mt++) {
#pragma unroll
      for (int nt = 0; nt < 2; nt++) {
        f32x4 a = acc[qd][mt][nt];
        size_t col = (size_t)wcol0 + hb * 128 + (w & 3) * 32 + nt * 16 + m16;
        float bvv = bias[col];
        size_t rowb = (size_t)arow0 + ha * 128 + (w >> 2) * 64 + mt * 16 + quad * 4;
#pragma unroll
        for (int r = 0; r < 4; r++)
          Cb[(rowb + r) * (size_t)N + col] = f2bf(gelu_f(a[r] + bvv));
      }
    }
  }
}

// ---------------- flash attention v7: 8 waves/block (zero grid tail), swizzled Ps, l-via-MFMA
// 512 blocks x 64KB LDS = exactly 2 blocks/CU (old: 1024 blocks @3/CU -> 33% idle 2nd round).
// Ps: stride 64 + 16B-chunk XOR swizzle (same pattern as K/V, measured 0 conflicts) replaces
// PSTR=72 (8-way read conflicts = 6.29M cycles/dispatch).
// l: accumulated via mfma(P, ones) on the MFMA pipe (removes 32 v_add/tile on the busier
// VALU pipe + the epilogue shuffle reduction; denominator now uses the same truncated-bf16
// P as the numerator -> self-consistent softmax).
__global__ void __launch_bounds__(512, 4) attn_kernel(const u16* __restrict__ qkv,
                                                      const u16* __restrict__ vtb,
                                                      u16* __restrict__ obuf)
{
  __shared__ u16 Ks[2][64 * 64];        // 16 KB
  __shared__ u16 Vs[2][64 * 64];        // 16 KB
  __shared__ u16 Ps[8][2][16 * 64];     // 32 KB   total 64 KB -> 2 blocks/CU

  const int tid = threadIdx.x;
  const int lane = tid & 63, wave = tid >> 6;     // wave 0..7
  const int m16 = lane & 15, quad = lane >> 4;
  const int bh = blockIdx.x;                      // XCD = bh&7: q-blocks of one bh co-locate
  const int b = bh >> 4, h = bh & 15;
  const int q0 = blockIdx.y * 256 + wave * 32;    // this wave: q0..q0+31

  const u16* base = qkv + ((size_t)b * KTOK) * (3 * D_) + h * DH_;
  const u16* vb   = vtb + (size_t)bh * 64 * KTOK; // rows = dh, stride KTOK

  short8 qf[2][2];
#pragma unroll
  for (int qh = 0; qh < 2; qh++) {
    const u16* qrow = base + (size_t)(q0 + qh * 16 + m16) * (3 * D_);
    qf[qh][0] = *(const short8*)(qrow + quad * 8);
    qf[qh][1] = *(const short8*)(qrow + 32 + quad * 8);
  }
  short8 vone;                         // bf16 1.0 broadcast (B-operand for l = P @ ones)
#pragma unroll
  for (int i = 0; i < 8; i++) vone[i] = (short)0x3F80;

  f32x4 oacc[2][4];
#pragma unroll
  for (int qh = 0; qh < 2; qh++)
#pragma unroll
    for (int nt = 0; nt < 4; nt++) oacc[qh][nt] = (f32x4)0.0f;
  f32x4 lacc[2] = {(f32x4)0.0f, (f32x4)0.0f};

  // stage one 64x64 u16 tile: 512 chunks of 16B, one gld_lds per thread
  auto stage_tile = [&](const u16* g0, size_t rstride, u16* lds) {
    int key = tid >> 3;
    int cc = (tid ^ key) & 7;
    gld_lds16(g0 + (size_t)key * rstride + cc * 8, lds + (size_t)(tid & ~63) * 8);
  };

  stage_tile(base + D_, 3 * D_, &Ks[0][0]);
  stage_tile(vb, KTOK, &Vs[0][0]);
  __syncthreads();

  const int sw = m16 & 7;
  int buf = 0;
  for (int tk = 0; tk < KTOK; tk += 64) {
    if (tk + 64 < KTOK) {
      stage_tile(base + (size_t)(tk + 64) * (3 * D_) + D_, 3 * D_, &Ks[buf ^ 1][0]);
      stage_tile(vb + (tk + 64), KTOK, &Vs[buf ^ 1][0]);
    }
    const u16* Kb = &Ks[buf][0];
    const u16* Vb = &Vs[buf][0];

    // ---- S^T = K Q^T ----
    f32x4 sacc[2][4];
#pragma unroll
    for (int qh = 0; qh < 2; qh++)
#pragma unroll
      for (int nt = 0; nt < 4; nt++) sacc[qh][nt] = (f32x4)0.0f;
    __builtin_amdgcn_s_setprio(1);
#pragma unroll
    for (int nt = 0; nt < 4; nt++) {
      int row = nt * 16 + m16;
      int ksw = row & 7;
      short8 kf0 = *(const short8*)&Kb[row * 64 + ((quad ^ ksw) * 8)];
      short8 kf1 = *(const short8*)&Kb[row * 64 + (((4 + quad) ^ ksw) * 8)];
#pragma unroll
      for (int qh = 0; qh < 2; qh++) {
        sacc[qh][nt] = __builtin_amdgcn_mfma_f32_16x16x32_bf16(kf0, qf[qh][0], sacc[qh][nt], 0, 0, 0);
        sacc[qh][nt] = __builtin_amdgcn_mfma_f32_16x16x32_bf16(kf1, qf[qh][1], sacc[qh][nt], 0, 0, 0);
      }
    }
    __builtin_amdgcn_s_setprio(0);

    // ---- hoisted V B-fragments ----
    short8 vf[4][2];
#pragma unroll
    for (int nt = 0; nt < 4; nt++) {
      int row = nt * 16 + m16;
      int vsw = row & 7;
      vf[nt][0] = *(const short8*)&Vb[row * 64 + ((quad ^ vsw) * 8)];
      vf[nt][1] = *(const short8*)&Vb[row * 64 + (((4 + quad) ^ vsw) * 8)];
    }

    // ---- exp2 + pack + swizzled store, both qh ----
#pragma unroll
    for (int qh = 0; qh < 2; qh++) {
#pragma unroll
      for (int nt = 0; nt < 4; nt++) {
        f32x4 p;
#pragma unroll
        for (int r = 0; r < 4; r++) p[r] = EXP2F(sacc[qh][nt][r]);
        u32x2 w2; w2[0] = pkbf_t(p[0], p[1]); w2[1] = pkbf_t(p[2], p[3]);
        int c16 = 2 * nt + (quad >> 1);           // 16B chunk within row
        *(u32x2*)&Ps[wave][qh][m16 * 64 + ((c16 ^ sw) * 8) + (quad & 1) * 4] = w2;
      }
    }
    // ---- swizzled P A-frag reads, then one PV + l MFMA cluster ----
    short8 pa[2][2];
#pragma unroll
    for (int qh = 0; qh < 2; qh++) {
      pa[qh][0] = *(const short8*)&Ps[wave][qh][m16 * 64 + ((quad ^ sw) * 8)];
      pa[qh][1] = *(const short8*)&Ps[wave][qh][m16 * 64 + (((4 + quad) ^ sw) * 8)];
    }
    __builtin_amdgcn_s_setprio(1);
#pragma unroll
    for (int qh = 0; qh < 2; qh++) {
#pragma unroll
      for (int nt = 0; nt < 4; nt++) {
        oacc[qh][nt] = __builtin_amdgcn_mfma_f32_16x16x32_bf16(pa[qh][0], vf[nt][0], oacc[qh][nt], 0, 0, 0);
        oacc[qh][nt] = __builtin_amdgcn_mfma_f32_16x16x32_bf16(pa[qh][1], vf[nt][1], oacc[qh][nt], 0, 0, 0);
      }
      lacc[qh] = __builtin_amdgcn_mfma_f32_16x16x32_bf16(pa[qh][0], vone, lacc[qh], 0, 0, 0);
      lacc[qh] = __builtin_amdgcn_mfma_f32_16x16x32_bf16(pa[qh][1], vone, lacc[qh], 0, 0, 0);
    }
    __builtin_amdgcn_s_setprio(0);

    __syncthreads();
    buf ^= 1;
  }

  // ---- epilogue: lacc[qh][r] already holds l for row q=quad*4+r in every lane ----
#pragma unroll
  for (int qh = 0; qh < 2; qh++) {
    f32x4 rl;
#pragma unroll
    for (int r = 0; r < 4; r++) rl[r] = 1.0f / lacc[qh][r];
#pragma unroll
    for (int nt = 0; nt < 4; nt++)
#pragma unroll
      for (int r = 0; r < 4; r++) {
        int qq = q0 + qh * 16 + quad * 4 + r;
        float v = oacc[qh][nt][r] * rl[r];
        obuf[((size_t)b * KTOK + qq) * D_ + h * DH_ + nt * 16 + m16] = f2bf(v);
      }
  }
}

// ---------------- launch ----------------
extern "C" void kernel_launch(void* const* d_in, const int* in_sizes, int n_in,
                              void* d_out, int out_size, void* d_ws, size_t ws_size,
                              hipStream_t stream)
{
  (void)in_sizes; (void)n_in; (void)out_size; (void)ws_size;
  const float* x          = (const float*)d_in[0];
  const float* w_router   = (const float*)d_in[1];
  const float* in_proj_w  = (const float*)d_in[2];
  const float* in_proj_b  = (const float*)d_in[3];
  const float* out_proj_w = (const float*)d_in[4];
  const float* out_proj_b = (const float*)d_in[5];
  const float* w1         = (const float*)d_in[6];
  const float* b1         = (const float*)d_in[7];
  const float* w2         = (const float*)d_in[8];
  const float* b2         = (const float*)d_in[9];
  const float* ln1g       = (const float*)d_in[10];
  const float* ln1b       = (const float*)d_in[11];
  const float* ln2g       = (const float*)d_in[12];
  const float* ln2b       = (const float*)d_in[13];
  float* out = (float*)d_out;

  char* w = (char*)d_ws;
  auto alloc = [&](size_t bytes) -> char* {
    char* p = w; w += (bytes + 255) & ~(size_t)255; return p;
  };
  float* logits = (float*)alloc((size_t)B_ * T_ * 4);
  int*   rnk    = (int*)  alloc((size_t)B_ * T_ * 4);
  int*   idx    = (int*)  alloc((size_t)B_ * KTOK * 4);
  float* auxacc = (float*)alloc(256);
  u16* inpw  = (u16*)alloc((size_t)3 * D_ * D_ * 2);
  u16* outpw = (u16*)alloc((size_t)D_ * D_ * 2);
  u16* w1b   = (u16*)alloc((size_t)4 * D_ * D_ * 2);
  u16* w2b   = (u16*)alloc((size_t)4 * D_ * D_ * 2);
  float* xs  = (float*)alloc((size_t)MROWS * D_ * 4);
  u16* hbuf  = (u16*)alloc((size_t)MROWS * D_ * 2);
  char* region = alloc((size_t)MROWS * 4 * D_ * 2);      // 64 MB: qkv(48)+obuf(16), reused by ff
  u16* qkvb = (u16*)region;
  u16* obuf = (u16*)(region + (size_t)MROWS * 3 * D_ * 2);
  u16* ffb  = (u16*)region;
  u16* vtb  = (u16*)alloc((size_t)B_ * H_ * DH_ * KTOK * 2);   // 16 MB: V transposed [bh][dh][tok]

  (void)hipMemsetAsync(auxacc, 0, 4, stream);
  (void)hipMemsetAsync(rnk, 0, (size_t)B_ * T_ * 4, stream);

  router_kernel<<<B_ * T_ / 4, 256, 0, stream>>>(x, w_router, logits, auxacc);
  rankp_kernel<<<dim3(T_ / 256, B_, 16), 256, 0, stream>>>(logits, rnk);
  lnpass_kernel<<<B_ * T_, 256, 0, stream>>>(x, rnk, ln1g, ln1b, xs, hbuf, out,
                                             idx, auxacc, out + (size_t)B_ * T_ * D_);

  f2bf_all<<<12 * D_ * D_ / 1024, 256, 0, stream>>>(in_proj_w, out_proj_w, w1, w2,
                                                    inpw, outpw, w1b, w2b);

  gemm_bt<0><<<dim3(3 * D_ / 128, MROWS / 128), 256, 0, stream>>>(
      hbuf, inpw, in_proj_b, nullptr, qkvb, nullptr, nullptr, vtb, MROWS, 3 * D_, D_);
  attn_kernel<<<dim3(B_ * H_, KTOK / 256), 512, 0, stream>>>(qkvb, vtb, obuf);
  gemm_bt<1><<<dim3(D_ / 128, MROWS / 128), 256, 0, stream>>>(
      obuf, outpw, out_proj_b, xs, nullptr, nullptr, nullptr, nullptr, MROWS, D_, D_);
  ln2_kernel<<<MROWS, 256, 0, stream>>>(xs, ln2g, ln2b, hbuf);
  gemm_ff1<<<dim3(4 * D_ / 256, MROWS / 256), 512, 0, stream>>>(
      hbuf, w1b, b1, ffb, MROWS, 4 * D_, D_);
  gemm_bt<3><<<dim3(D_ / 128, MROWS / 128), 256, 0, stream>>>(
      ffb, w2b, b2, xs, nullptr, out, idx, nullptr, MROWS, D_, 4 * D_);
}

// Round 8
// 634.784 us; speedup vs baseline: 1.0072x; 1.0072x over previous
//
#include <hip/hip_runtime.h>

#define B_    4
#define T_    4096
#define D_    1024
#define H_    16
#define DH_   64
#define KTOK  2048
#define MROWS (B_*KTOK)   // 8192

typedef unsigned short u16;
typedef __attribute__((ext_vector_type(8))) short short8;
typedef __attribute__((ext_vector_type(4))) float f32x4;
typedef __attribute__((ext_vector_type(4))) unsigned int u32x4;
typedef __attribute__((ext_vector_type(2))) unsigned int u32x2;
typedef __attribute__((ext_vector_type(4))) unsigned short u16x4;

static __device__ __forceinline__ u16 f2bf(float f) {
  union { float f; unsigned int u; } a; a.f = f;
  unsigned int u = a.u;
  unsigned int r = (u + 0x7FFFu + ((u >> 16) & 1u)) >> 16;   // RNE
  return (u16)r;
}

#if defined(__has_builtin)
#if __has_builtin(__builtin_amdgcn_exp2f)
#define EXP2F(x) __builtin_amdgcn_exp2f(x)
#endif
#endif
#ifndef EXP2F
#define EXP2F(x) exp2f(x)
#endif

// fast erf-based gelu: Abramowitz-Stegun 7.1.26, |err(erf)| < 2e-7 (vs bf16 ulp ~4e-3)
static __device__ __forceinline__ float gelu_f(float v) {
  float x = fabsf(v) * 0.70710678118654752f;
  float t = __builtin_amdgcn_rcpf(1.0f + 0.3275911f * x);
  float p = t * (0.254829592f + t * (-0.284496736f + t * (1.421413741f +
            t * (-1.453152027f + t * 1.061405429f))));
  float e = EXP2F(-1.4426950408889634f * x * x);
  float er = 1.0f - p * e;                    // erf(|x|)
  er = (v < 0.0f) ? -er : er;
  return 0.5f * v * (1.0f + er);
}

// pack two fp32 -> adjacent bf16 pair (low = a), TRUNCATING (1 v_perm).
static __device__ __forceinline__ unsigned int pkbf_t(float a, float b) {
  unsigned int ua = __builtin_bit_cast(unsigned int, a);
  unsigned int ub = __builtin_bit_cast(unsigned int, b);
  return __builtin_amdgcn_perm(ub, ua, 0x07060302u);  // [ua.hi16 low, ub.hi16 high]
}

static __device__ __forceinline__ void gld_lds16(const u16* g, u16* l) {
  __builtin_amdgcn_global_load_lds((__attribute__((address_space(1))) void*)g,
                                   (__attribute__((address_space(3))) void*)l, 16, 0, 0);
}

#define WAITV(N) asm volatile("s_waitcnt vmcnt(" #N ")" ::: "memory")

// ---------------- router: logits = x @ w_router, accumulate sum(logits^2) ----------------
__global__ void __launch_bounds__(256) router_kernel(const float* __restrict__ x,
    const float* __restrict__ wr, float* __restrict__ logits, float* __restrict__ auxacc)
{
  int tid = threadIdx.x; int lane = tid & 63, wave = tid >> 6;
  int row = blockIdx.x * 4 + wave;                 // 0 .. B*T-1
  const float* xr = x + (size_t)row * D_;
  float dot = 0.f;
#pragma unroll
  for (int j = 0; j < 4; j++) {
    int c = j * 256 + lane * 4;
    f32x4 xv = *(const f32x4*)(xr + c);
    f32x4 wv = *(const f32x4*)(wr + c);
    dot += xv[0]*wv[0] + xv[1]*wv[1] + xv[2]*wv[2] + xv[3]*wv[3];
  }
#pragma unroll
  for (int d = 1; d < 64; d <<= 1) dot += __shfl_xor(dot, d);
  __shared__ float red[4];
  if (lane == 0) { logits[row] = dot; red[wave] = dot; }
  __syncthreads();
  if (tid == 0) {
    float a = red[0]*red[0] + red[1]*red[1] + red[2]*red[2] + red[3]*red[3];
    atomicAdd(auxacc, a);
  }
}

// -------- partial rank: grid (T/256, B, 16 chunks); atomicAdd partial counts into rnk ------
__global__ void __launch_bounds__(256) rankp_kernel(const float* __restrict__ logits,
    int* __restrict__ rnk)
{
  __shared__ float ll[256];
  const int b = blockIdx.y, ch = blockIdx.z;
  const int tid = threadIdx.x;
  const float* lg = logits + (size_t)b * T_;
  const int j0 = ch * 256;
  ll[tid] = lg[j0 + tid];
  __syncthreads();
  const int t = blockIdx.x * 256 + tid;
  const float my = lg[t];
  int rank = 0;
#pragma unroll 4
  for (int j = 0; j < 256; j += 4) {
    f32x4 lj = *(const f32x4*)&ll[j];
    int jg = j0 + j;
    rank += (lj[0] > my) || (lj[0] == my && (jg+0) < t);
    rank += (lj[1] > my) || (lj[1] == my && (jg+1) < t);
    rank += (lj[2] > my) || (lj[2] == my && (jg+2) < t);
    rank += (lj[3] > my) || (lj[3] == my && (jg+3) < t);
  }
  atomicAdd(&rnk[(size_t)b * T_ + t], rank);
}

// ---------------- fused: pass-through unselected OR gather+LN selected; builds idx --------
__global__ void __launch_bounds__(256) lnpass_kernel(const float* __restrict__ x,
    const int* __restrict__ rnk, const float* __restrict__ g, const float* __restrict__ bb,
    float* __restrict__ xs_out, u16* __restrict__ hout, float* __restrict__ out,
    int* __restrict__ idx, const float* __restrict__ acc, float* __restrict__ auxout)
{
  int row = blockIdx.x;            // 0 .. B*T-1
  int tid = threadIdx.x;
  if (row == 0 && tid == 0) auxout[0] = acc[0] * (0.01f / (float)(B_ * T_));
  const float* srow = x + (size_t)row * D_;
  f32x4 v = *(const f32x4*)(srow + tid * 4);
  int r = rnk[row];                // block-uniform
  if (r >= KTOK) {                 // unselected: copy x row to out
    *(f32x4*)(out + (size_t)row * D_ + tid * 4) = v;
    return;
  }
  if (tid == 0) idx[(row >> 12) * KTOK + r] = row & (T_ - 1);   // T_=4096
  size_t mrow = (size_t)(row >> 12) * KTOK + r;
  float s  = v[0] + v[1] + v[2] + v[3];
  float sq = v[0]*v[0] + v[1]*v[1] + v[2]*v[2] + v[3]*v[3];
#pragma unroll
  for (int d = 1; d < 64; d <<= 1) { s += __shfl_xor(s, d); sq += __shfl_xor(sq, d); }
  __shared__ float rs[4], rq[4];
  int lane = tid & 63, wave = tid >> 6;
  if (lane == 0) { rs[wave] = s; rq[wave] = sq; }
  __syncthreads();
  s  = rs[0] + rs[1] + rs[2] + rs[3];
  sq = rq[0] + rq[1] + rq[2] + rq[3];
  float mean = s * (1.0f / D_);
  float var  = sq * (1.0f / D_) - mean * mean;
  float rstd = rsqrtf(var + 1e-5f);
  f32x4 gg = *(const f32x4*)(g + tid * 4);
  f32x4 bv = *(const f32x4*)(bb + tid * 4);
  *(f32x4*)(xs_out + mrow * D_ + tid * 4) = v;
  u16x4 o;
#pragma unroll
  for (int j = 0; j < 4; j++) o[j] = f2bf((v[j] - mean) * rstd * gg[j] + bv[j]);
  *(u16x4*)(hout + mrow * D_ + tid * 4) = o;
}

// ---------------- LayerNorm (no gather) ----------------
__global__ void __launch_bounds__(256) ln2_kernel(const float* __restrict__ src,
    const float* __restrict__ g, const float* __restrict__ bb, u16* __restrict__ hout)
{
  int row = blockIdx.x;
  int tid = threadIdx.x;
  const float* srow = src + (size_t)row * D_;
  f32x4 v = *(const f32x4*)(srow + tid * 4);
  float s  = v[0] + v[1] + v[2] + v[3];
  float sq = v[0]*v[0] + v[1]*v[1] + v[2]*v[2] + v[3]*v[3];
#pragma unroll
  for (int d = 1; d < 64; d <<= 1) { s += __shfl_xor(s, d); sq += __shfl_xor(sq, d); }
  __shared__ float rs[4], rq[4];
  int lane = tid & 63, wave = tid >> 6;
  if (lane == 0) { rs[wave] = s; rq[wave] = sq; }
  __syncthreads();
  s  = rs[0] + rs[1] + rs[2] + rs[3];
  sq = rq[0] + rq[1] + rq[2] + rq[3];
  float mean = s * (1.0f / D_);
  float var  = sq * (1.0f / D_) - mean * mean;
  float rstd = rsqrtf(var + 1e-5f);
  f32x4 gg = *(const f32x4*)(g + tid * 4);
  f32x4 bv = *(const f32x4*)(bb + tid * 4);
  u16x4 o;
#pragma unroll
  for (int j = 0; j < 4; j++) o[j] = f2bf((v[j] - mean) * rstd * gg[j] + bv[j]);
  *(u16x4*)(hout + (size_t)row * D_ + tid * 4) = o;
}

// ---------------- fp32 -> bf16 convert, all 4 weight matrices in one dispatch ----------------
__global__ void __launch_bounds__(256) f2bf_all(const float* __restrict__ s0, const float* __restrict__ s1,
    const float* __restrict__ s2, const float* __restrict__ s3,
    u16* __restrict__ d0, u16* __restrict__ d1, u16* __restrict__ d2, u16* __restrict__ d3)
{
  const size_t c0 = (size_t)3 * D_ * D_, c1 = (size_t)4 * D_ * D_, c2 = (size_t)8 * D_ * D_;
  size_t e = (size_t)blockIdx.x * 1024 + (size_t)threadIdx.x * 4;
  const float* s; u16* d; size_t off;
  if (e < c0)      { s = s0; d = d0; off = e; }
  else if (e < c1) { s = s1; d = d1; off = e - c0; }
  else if (e < c2) { s = s2; d = d2; off = e - c1; }
  else             { s = s3; d = d3; off = e - c2; }
  f32x4 v = *(const f32x4*)(s + off);
  u16x4 o; o[0]=f2bf(v[0]); o[1]=f2bf(v[1]); o[2]=f2bf(v[2]); o[3]=f2bf(v[3]);
  *(u16x4*)(d + off) = o;
}

// ========== GEMM 128x128, BK=64, 4 row-waves, deep-prefetch schedule ===========
// AHM: A is head-major [b][h=ktile][q][64] (attn obuf layout); BK=64==DH so one k-tile is
// exactly one head: row stride 64, k-tile stride KTOK*64. LDS side & math identical.
template<int EPI, bool AHM = false>
__global__ void __launch_bounds__(256, 2) gemm_bt(
    const u16* __restrict__ A, const u16* __restrict__ W,
    const float* __restrict__ bias, float* __restrict__ xs,
    u16* __restrict__ Cb, float* __restrict__ outf,
    const int* __restrict__ idx, u16* __restrict__ vtb, int M, int N, int K)
{
  __shared__ u16 As[2][128 * 64];
  __shared__ u16 Ws[2][128 * 64];
  const int tid = threadIdx.x;
  const int lane = tid & 63, wave = tid >> 6;
  const int m16 = lane & 15, quad = (lane >> 4) & 3;

  // chunked bijective XCD swizzle (grid divisible by 8)
  const int gx = gridDim.x;
  const int id = blockIdx.y * gx + blockIdx.x;
  const int cpx = (gx * (int)gridDim.y) >> 3;
  const int tl = (id & 7) * cpx + (id >> 3);
  const int bx = tl % gx, by = tl / gx;

  const size_t arow0 = (size_t)by * 128;
  const size_t wrow0 = (size_t)bx * 128;

  // stage one [64][64] u16 piece (8KB = 512 chunks), thread t -> chunks t, 256+t
  const int trow = tid >> 3;                // 0..31
  const int tcc  = (tid ^ trow) & 7;        // swizzled source col-chunk (inverse of read XOR)
  auto stagepc = [&](const u16* g0, size_t rs, u16* l0) {
    gld_lds16(g0 + (size_t)trow * rs + tcc * 8,        l0 + (size_t)(tid & ~63) * 8);
    gld_lds16(g0 + (size_t)(32 + trow) * rs + tcc * 8, l0 + 2048 + (size_t)(tid & ~63) * 8);
  };
  auto stage_tile = [&](int u, int s) {     // FIFO: Ar0, Ar1, B0, B1
    size_t kn = (size_t)u * 64;
    if (AHM) {
      const u16* Ab = A + (arow0 >> 11) * (size_t)(H_ * KTOK * DH_)
                        + (arow0 & (KTOK - 1)) * DH_ + (size_t)u * (KTOK * DH_);
      stagepc(Ab,            64, &As[s][0]);
      stagepc(Ab + 64 * 64,  64, &As[s][64 * 64]);
    } else {
      stagepc(A + (arow0)      * K + kn, K, &As[s][0]);
      stagepc(A + (arow0 + 64) * K + kn, K, &As[s][64 * 64]);
    }
    stagepc(W + (wrow0)      * K + kn, K, &Ws[s][0]);
    stagepc(W + (wrow0 + 64) * K + kn, K, &Ws[s][64 * 64]);
  };

  auto ldA = [&](short8 (&f)[2][2], const u16* h) {
#pragma unroll
    for (int mt = 0; mt < 2; mt++) {
      int rr = wave * 32 + mt * 16 + m16;
      int sw = rr & 7;
#pragma unroll
      for (int kk = 0; kk < 2; kk++)
        f[mt][kk] = *(const short8*)&h[rr * 64 + (((kk * 4 + quad) ^ sw) * 8)];
    }
  };
  auto ldB = [&](short8 (&f)[4][2], const u16* h, int half) {
#pragma unroll
    for (int nt = 0; nt < 4; nt++) {
      int rb = half * 64 + nt * 16 + m16;
      int sw = rb & 7;
#pragma unroll
      for (int kk = 0; kk < 2; kk++)
        f[nt][kk] = *(const short8*)&h[rb * 64 + (((kk * 4 + quad) ^ sw) * 8)];
    }
  };

  f32x4 acc[2][8];
#pragma unroll
  for (int mt = 0; mt < 2; mt++)
#pragma unroll
    for (int n = 0; n < 8; n++) acc[mt][n] = (f32x4)0.0f;

  stage_tile(0, 0);

  const int NT = K >> 6;
  short8 af[2][2], bf[4][2], bf2[4][2];

  for (int t = 0; t < NT; t++) {
    const int cur = t & 1;
    const bool last = (t == NT - 1);

    WAITV(2);                                  // Ar0,Ar1,B0(t) done (issued full tile ago)
    __builtin_amdgcn_s_barrier();
    __builtin_amdgcn_sched_barrier(0);
    if (!last) stage_tile(t + 1, cur ^ 1);

    // p0: cols 0-63
    ldA(af, &As[cur][0]);
    ldB(bf, &Ws[cur][0], 0);
    __builtin_amdgcn_s_setprio(1);
#pragma unroll
    for (int mt = 0; mt < 2; mt++)
#pragma unroll
      for (int nt = 0; nt < 4; nt++)
#pragma unroll
        for (int kk = 0; kk < 2; kk++)
          acc[mt][nt] = __builtin_amdgcn_mfma_f32_16x16x32_bf16(af[mt][kk], bf[nt][kk], acc[mt][nt], 0, 0, 0);
    __builtin_amdgcn_s_setprio(0);

    if (last) { WAITV(0); } else { WAITV(8); } // B1(t) done; t+1's 8 loads stay in flight
    __builtin_amdgcn_s_barrier();
    __builtin_amdgcn_sched_barrier(0);

    // p1: cols 64-127 (barrier-free drift region)
    ldB(bf2, &Ws[cur][0], 1);
    __builtin_amdgcn_s_setprio(1);
#pragma unroll
    for (int mt = 0; mt < 2; mt++)
#pragma unroll
      for (int nt = 0; nt < 4; nt++)
#pragma unroll
        for (int kk = 0; kk < 2; kk++)
          acc[mt][4 + nt] = __builtin_amdgcn_mfma_f32_16x16x32_bf16(af[mt][kk], bf2[nt][kk], acc[mt][4 + nt], 0, 0, 0);
    __builtin_amdgcn_s_setprio(0);
  }

  // ---- epilogue ----
#pragma unroll
  for (int half = 0; half < 2; half++) {
#pragma unroll
    for (int mt = 0; mt < 2; mt++) {
#pragma unroll
      for (int nt = 0; nt < 4; nt++) {
        f32x4 a = acc[mt][half * 4 + nt];
        size_t col = wrow0 + half * 64 + nt * 16 + m16;
        float bvv = bias[col];
        size_t rowb = arow0 + wave * 32 + mt * 16 + quad * 4;
        if (EPI == 0) {
          if ((int)col < 2 * D_) {
            float sc = ((int)col < D_) ? 0.18033688f : 1.0f;  // fold 1/sqrt(dh)*log2(e) into Q
#pragma unroll
            for (int r = 0; r < 4; r++)
              Cb[(rowb + r) * (size_t)N + col] = f2bf((a[r] + bvv) * sc);
          } else {
            int hdh = (int)col - 2 * D_;
            int bb2 = (int)(rowb >> 11);
            int tok = (int)(rowb & (KTOK - 1));
            u16x4 o;
#pragma unroll
            for (int r = 0; r < 4; r++) o[r] = f2bf(a[r] + bvv);
            *(u16x4*)&vtb[(((size_t)(bb2 * H_) + (hdh >> 6)) * 64 + (hdh & 63)) * KTOK + tok] = o;
          }
        } else if (EPI == 1) {
#pragma unroll
          for (int r = 0; r < 4; r++) {
            size_t o = (rowb + r) * (size_t)N + col;
            xs[o] = xs[o] + (a[r] + bvv);
          }
        } else {
#pragma unroll
          for (int r = 0; r < 4; r++) {
            size_t row = rowb + r;
            int b = (int)(row >> 11);
            int i = (int)(row & (KTOK - 1));
            int t = idx[b * KTOK + i];
            float vv = xs[row * (size_t)D_ + col] + (a[r] + bvv);
            outf[((size_t)b * T_ + t) * D_ + col] = vv;
          }
        }
      }
    }
  }
}

// ================= FF1 GEMM: 256x256, BK=64, 512 threads, deep-prefetch schedule ===========
__global__ void __launch_bounds__(512, 1) gemm_ff1(
    const u16* __restrict__ A, const u16* __restrict__ W,
    const float* __restrict__ bias, u16* __restrict__ Cb, int M, int N, int K)
{
  __shared__ u16 Asm[2][2][128 * 64];
  __shared__ u16 Bsm[2][2][128 * 64];

  const int tid = threadIdx.x;
  const int lane = tid & 63;
  const int w = tid >> 6;                  // wave 0..7
  const int m16 = lane & 15, quad = (lane >> 4) & 3;
  const int rowA = (w >> 2) * 64;          // within A-half
  const int rowB = (w & 3) * 32;           // within B-half

  const int gx = gridDim.x;
  const int id = blockIdx.y * gx + blockIdx.x;
  const int cpx = (gx * (int)gridDim.y) >> 3;
  const int tl = (id & 7) * cpx + (id >> 3);
  const int bx = tl % gx, by = tl / gx;

  const int arow0 = by * 256;
  const int wcol0 = bx * 256;

  const int th8 = tid >> 3;
  const int ccs = (tid ^ th8) & 7;
  auto stage = [&](const u16* g0, u16* l0) {       // one 128x64 half-tile (16KB), 2 loads/thread
    gld_lds16(g0 + (size_t)th8 * K + ccs * 8,        l0 + (size_t)(tid & ~63) * 8);
    gld_lds16(g0 + (size_t)(64 + th8) * K + ccs * 8, l0 + 4096 + (size_t)(tid & ~63) * 8);
  };
  auto stage_tile = [&](int u, int s) {            // FIFO order: A0, B0, A1, B1
    size_t kn = (size_t)u * 64;
    stage(A + (size_t)arow0 * K + kn,         &Asm[s][0][0]);
    stage(W + (size_t)wcol0 * K + kn,         &Bsm[s][0][0]);
    stage(A + (size_t)(arow0 + 128) * K + kn, &Asm[s][1][0]);
    stage(W + (size_t)(wcol0 + 128) * K + kn, &Bsm[s][1][0]);
  };

  auto ldA = [&](short8 (&f)[4][2], const u16* h) {
#pragma unroll
    for (int mt = 0; mt < 4; mt++) {
      int rr = rowA + mt * 16 + m16;
      int sw = rr & 7;
#pragma unroll
      for (int kk = 0; kk < 2; kk++)
        f[mt][kk] = *(const short8*)&h[rr * 64 + (((kk * 4 + quad) ^ sw) * 8)];
    }
  };
  auto ldB = [&](short8 (&f)[2][2], const u16* h) {
#pragma unroll
    for (int nt = 0; nt < 2; nt++) {
      int rb = rowB + nt * 16 + m16;
      int sw = rb & 7;
#pragma unroll
      for (int kk = 0; kk < 2; kk++)
        f[nt][kk] = *(const short8*)&h[rb * 64 + (((kk * 4 + quad) ^ sw) * 8)];
    }
  };

  f32x4 acc[4][4][2];
#pragma unroll
  for (int q = 0; q < 4; q++)
#pragma unroll
    for (int mt = 0; mt < 4; mt++)
#pragma unroll
      for (int nt = 0; nt < 2; nt++) acc[q][mt][nt] = (f32x4)0.0f;

#define MMQ(QD, FA, FB) do { \
  __builtin_amdgcn_s_setprio(1); \
  _Pragma("unroll") for (int mt = 0; mt < 4; mt++) \
  _Pragma("unroll") for (int nt = 0; nt < 2; nt++) \
  _Pragma("unroll") for (int kk = 0; kk < 2; kk++) \
    acc[QD][mt][nt] = __builtin_amdgcn_mfma_f32_16x16x32_bf16(FA[mt][kk], FB[nt][kk], acc[QD][mt][nt], 0, 0, 0); \
  __builtin_amdgcn_s_setprio(0); } while (0)

  stage_tile(0, 0);

  const int NT = K >> 6;
  short8 af[4][2], af2[4][2], bf[2][2], bf2[2][2];

  for (int t = 0; t < NT; t++) {
    const int cur = t & 1;
    const bool last = (t == NT - 1);

    WAITV(4);                                   // A0,B0(t) done; A1,B1(t) may be in flight
    __builtin_amdgcn_s_barrier();
    __builtin_amdgcn_sched_barrier(0);
    if (!last) stage_tile(t + 1, cur ^ 1);      // 8 loads; slots freed by this barrier

    // p0: (A0,B0)
    ldA(af, &Asm[cur][0][0]);
    ldB(bf, &Bsm[cur][0][0]);
    MMQ(0, af, bf);

    if (last) { WAITV(0); } else { WAITV(8); }  // A1,B1(t) done; t+1's 8 loads in flight
    __builtin_amdgcn_s_barrier();
    __builtin_amdgcn_sched_barrier(0);

    // p1..p3: barrier-free drift region
    ldB(bf2, &Bsm[cur][1][0]);
    MMQ(1, af, bf2);
    ldA(af2, &Asm[cur][1][0]);
    MMQ(2, af2, bf);
    MMQ(3, af2, bf2);
  }
#undef MMQ

  // ---- epilogue: gelu(bf16) ----
#pragma unroll
  for (int qd = 0; qd < 4; qd++) {
    const int ha = qd >> 1, hb = qd & 1;
#pragma unroll
    for (int mt = 0; mt < 4; mt++) {
#pragma unroll
      for (int nt = 0; nt < 2; nt++) {
        f32x4 a = acc[qd][mt][nt];
        size_t col = (size_t)wcol0 + hb * 128 + (w & 3) * 32 + nt * 16 + m16;
        float bvv = bias[col];
        size_t rowb = (size_t)arow0 + ha * 128 + (w >> 2) * 64 + mt * 16 + quad * 4;
#pragma unroll
        for (int r = 0; r < 4; r++)
          Cb[(rowb + r) * (size_t)N + col] = f2bf(gelu_f(a[r] + bvv));
      }
    }
  }
}

// ---------------- flash attention v8: triple-buffer K/V, depth-2 prefetch, counted waits ---
// Stage tile t+2 at the TOP of tile t; end-of-tile barrier uses WAITV(2) — waits only for
// t+1's loads (issued TWO tiles = ~7K cycles earlier; covers 900cy HBM misses), leaving
// t+2's 2 loads in flight. Raw s_barrier (gld_lds completion is vmcnt, Ps is own-wave-only,
// K/V frag reads are lgkm'd by data deps). obuf now head-major [bh][q][dh]: contiguous
// 256KB per bh kills the cross-XCD 256B-line false sharing (v7: WRITE_SIZE 30.7MB vs 16.7MB
// actual -> ~2x write amplification).
__global__ void __launch_bounds__(512, 2) attn_kernel(const u16* __restrict__ qkv,
                                                      const u16* __restrict__ vtb,
                                                      u16* __restrict__ obuf)
{
  __shared__ u16 Ks[3][64 * 64];        // 24 KB
  __shared__ u16 Vs[3][64 * 64];        // 24 KB
  __shared__ u16 Ps[8][2][16 * 64];     // 32 KB   total 80 KB -> 2 blocks/CU

  const int tid = threadIdx.x;
  const int lane = tid & 63, wave = tid >> 6;     // wave 0..7
  const int m16 = lane & 15, quad = lane >> 4;
  const int bh = blockIdx.x;                      // XCD = bh&7: q-blocks of one bh co-locate
  const int b = bh >> 4, h = bh & 15;
  const int q0 = blockIdx.y * 256 + wave * 32;    // this wave: q0..q0+31

  const u16* base = qkv + ((size_t)b * KTOK) * (3 * D_) + h * DH_;
  const u16* vb   = vtb + (size_t)bh * 64 * KTOK; // rows = dh, stride KTOK

  short8 qf[2][2];
#pragma unroll
  for (int qh = 0; qh < 2; qh++) {
    const u16* qrow = base + (size_t)(q0 + qh * 16 + m16) * (3 * D_);
    qf[qh][0] = *(const short8*)(qrow + quad * 8);
    qf[qh][1] = *(const short8*)(qrow + 32 + quad * 8);
  }
  short8 vone;                         // bf16 1.0 broadcast (B-operand for l = P @ ones)
#pragma unroll
  for (int i = 0; i < 8; i++) vone[i] = (short)0x3F80;

  f32x4 oacc[2][4];
#pragma unroll
  for (int qh = 0; qh < 2; qh++)
#pragma unroll
    for (int nt = 0; nt < 4; nt++) oacc[qh][nt] = (f32x4)0.0f;
  f32x4 lacc[2] = {(f32x4)0.0f, (f32x4)0.0f};

  // stage one 64x64 u16 tile: 512 chunks of 16B, one gld_lds per thread
  auto stage_kv = [&](int u, int s) {
    int key = tid >> 3;
    int cc = (tid ^ key) & 7;
    gld_lds16(base + (size_t)(u * 64 + key) * (3 * D_) + D_ + cc * 8,
              &Ks[s][0] + (size_t)(tid & ~63) * 8);
    gld_lds16(vb + (u * 64) + (size_t)key * KTOK + cc * 8,
              &Vs[s][0] + (size_t)(tid & ~63) * 8);
  };

  const int NT = KTOK / 64;                      // 32
  stage_kv(0, 0);                                // 2 loads
  stage_kv(1, 1);                                // 2 loads
  WAITV(2);                                      // tile 0 ready; tile 1 in flight
  __builtin_amdgcn_s_barrier();
  __builtin_amdgcn_sched_barrier(0);

  const int sw = m16 & 7;
  int buf = 0;
  for (int t = 0; t < NT; t++) {
    if (t + 2 < NT) {
      int s2 = buf + 2; if (s2 >= 3) s2 -= 3;
      stage_kv(t + 2, s2);                       // lands 2 tiles ahead of use
    }
    const u16* Kb = &Ks[buf][0];
    const u16* Vb = &Vs[buf][0];

    // ---- S^T = K Q^T ----
    f32x4 sacc[2][4];
#pragma unroll
    for (int qh = 0; qh < 2; qh++)
#pragma unroll
      for (int nt = 0; nt < 4; nt++) sacc[qh][nt] = (f32x4)0.0f;
    __builtin_amdgcn_s_setprio(1);
#pragma unroll
    for (int nt = 0; nt < 4; nt++) {
      int row = nt * 16 + m16;
      int ksw = row & 7;
      short8 kf0 = *(const short8*)&Kb[row * 64 + ((quad ^ ksw) * 8)];
      short8 kf1 = *(const short8*)&Kb[row * 64 + (((4 + quad) ^ ksw) * 8)];
#pragma unroll
      for (int qh = 0; qh < 2; qh++) {
        sacc[qh][nt] = __builtin_amdgcn_mfma_f32_16x16x32_bf16(kf0, qf[qh][0], sacc[qh][nt], 0, 0, 0);
        sacc[qh][nt] = __builtin_amdgcn_mfma_f32_16x16x32_bf16(kf1, qf[qh][1], sacc[qh][nt], 0, 0, 0);
      }
    }
    __builtin_amdgcn_s_setprio(0);

    // ---- hoisted V B-fragments ----
    short8 vf[4][2];
#pragma unroll
    for (int nt = 0; nt < 4; nt++) {
      int row = nt * 16 + m16;
      int vsw = row & 7;
      vf[nt][0] = *(const short8*)&Vb[row * 64 + ((quad ^ vsw) * 8)];
      vf[nt][1] = *(const short8*)&Vb[row * 64 + (((4 + quad) ^ vsw) * 8)];
    }

    // ---- exp2 + pack + swizzled store, both qh ----
#pragma unroll
    for (int qh = 0; qh < 2; qh++) {
#pragma unroll
      for (int nt = 0; nt < 4; nt++) {
        f32x4 p;
#pragma unroll
        for (int r = 0; r < 4; r++) p[r] = EXP2F(sacc[qh][nt][r]);
        u32x2 w2; w2[0] = pkbf_t(p[0], p[1]); w2[1] = pkbf_t(p[2], p[3]);
        int c16 = 2 * nt + (quad >> 1);           // 16B chunk within row
        *(u32x2*)&Ps[wave][qh][m16 * 64 + ((c16 ^ sw) * 8) + (quad & 1) * 4] = w2;
      }
    }
    // ---- swizzled P A-frag reads, then one PV + l MFMA cluster ----
    short8 pa[2][2];
#pragma unroll
    for (int qh = 0; qh < 2; qh++) {
      pa[qh][0] = *(const short8*)&Ps[wave][qh][m16 * 64 + ((quad ^ sw) * 8)];
      pa[qh][1] = *(const short8*)&Ps[wave][qh][m16 * 64 + (((4 + quad) ^ sw) * 8)];
    }
    __builtin_amdgcn_s_setprio(1);
#pragma unroll
    for (int qh = 0; qh < 2; qh++) {
#pragma unroll
      for (int nt = 0; nt < 4; nt++) {
        oacc[qh][nt] = __builtin_amdgcn_mfma_f32_16x16x32_bf16(pa[qh][0], vf[nt][0], oacc[qh][nt], 0, 0, 0);
        oacc[qh][nt] = __builtin_amdgcn_mfma_f32_16x16x32_bf16(pa[qh][1], vf[nt][1], oacc[qh][nt], 0, 0, 0);
      }
      lacc[qh] = __builtin_amdgcn_mfma_f32_16x16x32_bf16(pa[qh][0], vone, lacc[qh], 0, 0, 0);
      lacc[qh] = __builtin_amdgcn_mfma_f32_16x16x32_bf16(pa[qh][1], vone, lacc[qh], 0, 0, 0);
    }
    __builtin_amdgcn_s_setprio(0);

    if (t < NT - 1) {
      if (t < NT - 2) { WAITV(2); } else { WAITV(0); }   // t+1 ready; t+2 stays in flight
      __builtin_amdgcn_s_barrier();
      __builtin_amdgcn_sched_barrier(0);
    }
    buf = (buf == 2) ? 0 : buf + 1;
  }

  // ---- epilogue: lacc[qh][r] holds l for row q=quad*4+r; obuf head-major [bh][q][dh] ----
#pragma unroll
  for (int qh = 0; qh < 2; qh++) {
    f32x4 rl;
#pragma unroll
    for (int r = 0; r < 4; r++) rl[r] = 1.0f / lacc[qh][r];
#pragma unroll
    for (int nt = 0; nt < 4; nt++)
#pragma unroll
      for (int r = 0; r < 4; r++) {
        int qq = q0 + qh * 16 + quad * 4 + r;
        float v = oacc[qh][nt][r] * rl[r];
        obuf[((size_t)bh * KTOK + qq) * DH_ + nt * 16 + m16] = f2bf(v);
      }
  }
}

// ---------------- launch ----------------
extern "C" void kernel_launch(void* const* d_in, const int* in_sizes, int n_in,
                              void* d_out, int out_size, void* d_ws, size_t ws_size,
                              hipStream_t stream)
{
  (void)in_sizes; (void)n_in; (void)out_size; (void)ws_size;
  const float* x          = (const float*)d_in[0];
  const float* w_router   = (const float*)d_in[1];
  const float* in_proj_w  = (const float*)d_in[2];
  const float* in_proj_b  = (const float*)d_in[3];
  const float* out_proj_w = (const float*)d_in[4];
  const float* out_proj_b = (const float*)d_in[5];
  const float* w1         = (const float*)d_in[6];
  const float* b1         = (const float*)d_in[7];
  const float* w2         = (const float*)d_in[8];
  const float* b2         = (const float*)d_in[9];
  const float* ln1g       = (const float*)d_in[10];
  const float* ln1b       = (const float*)d_in[11];
  const float* ln2g       = (const float*)d_in[12];
  const float* ln2b       = (const float*)d_in[13];
  float* out = (float*)d_out;

  char* w = (char*)d_ws;
  auto alloc = [&](size_t bytes) -> char* {
    char* p = w; w += (bytes + 255) & ~(size_t)255; return p;
  };
  float* logits = (float*)alloc((size_t)B_ * T_ * 4);
  int*   rnk    = (int*)  alloc((size_t)B_ * T_ * 4);
  int*   idx    = (int*)  alloc((size_t)B_ * KTOK * 4);
  float* auxacc = (float*)alloc(256);
  u16* inpw  = (u16*)alloc((size_t)3 * D_ * D_ * 2);
  u16* outpw = (u16*)alloc((size_t)D_ * D_ * 2);
  u16* w1b   = (u16*)alloc((size_t)4 * D_ * D_ * 2);
  u16* w2b   = (u16*)alloc((size_t)4 * D_ * D_ * 2);
  float* xs  = (float*)alloc((size_t)MROWS * D_ * 4);
  u16* hbuf  = (u16*)alloc((size_t)MROWS * D_ * 2);
  char* region = alloc((size_t)MROWS * 4 * D_ * 2);      // 64 MB: qkv(48)+obuf(16), reused by ff
  u16* qkvb = (u16*)region;
  u16* obuf = (u16*)(region + (size_t)MROWS * 3 * D_ * 2);
  u16* ffb  = (u16*)region;
  u16* vtb  = (u16*)alloc((size_t)B_ * H_ * DH_ * KTOK * 2);   // 16 MB: V transposed [bh][dh][tok]

  (void)hipMemsetAsync(auxacc, 0, 4, stream);
  (void)hipMemsetAsync(rnk, 0, (size_t)B_ * T_ * 4, stream);

  router_kernel<<<B_ * T_ / 4, 256, 0, stream>>>(x, w_router, logits, auxacc);
  rankp_kernel<<<dim3(T_ / 256, B_, 16), 256, 0, stream>>>(logits, rnk);
  lnpass_kernel<<<B_ * T_, 256, 0, stream>>>(x, rnk, ln1g, ln1b, xs, hbuf, out,
                                             idx, auxacc, out + (size_t)B_ * T_ * D_);

  f2bf_all<<<12 * D_ * D_ / 1024, 256, 0, stream>>>(in_proj_w, out_proj_w, w1, w2,
                                                    inpw, outpw, w1b, w2b);

  gemm_bt<0><<<dim3(3 * D_ / 128, MROWS / 128), 256, 0, stream>>>(
      hbuf, inpw, in_proj_b, nullptr, qkvb, nullptr, nullptr, vtb, MROWS, 3 * D_, D_);
  attn_kernel<<<dim3(B_ * H_, KTOK / 256), 512, 0, stream>>>(qkvb, vtb, obuf);
  gemm_bt<1, true><<<dim3(D_ / 128, MROWS / 128), 256, 0, stream>>>(
      obuf, outpw, out_proj_b, xs, nullptr, nullptr, nullptr, nullptr, MROWS, D_, D_);
  ln2_kernel<<<MROWS, 256, 0, stream>>>(xs, ln2g, ln2b, hbuf);
  gemm_ff1<<<dim3(4 * D_ / 256, MROWS / 256), 512, 0, stream>>>(
      hbuf, w1b, b1, ffb, MROWS, 4 * D_, D_);
  gemm_bt<3><<<dim3(D_ / 128, MROWS / 128), 256, 0, stream>>>(
      ffb, w2b, b2, xs, nullptr, out, idx, nullptr, MROWS, D_, 4 * D_);
}

// Round 9
// 616.409 us; speedup vs baseline: 1.0372x; 1.0298x over previous
//
#include <hip/hip_runtime.h>

#define B_    4
#define T_    4096
#define D_    1024
#define H_    16
#define DH_   64
#define KTOK  2048
#define MROWS (B_*KTOK)   // 8192

typedef unsigned short u16;
typedef __attribute__((ext_vector_type(8))) short short8;
typedef __attribute__((ext_vector_type(4))) float f32x4;
typedef __attribute__((ext_vector_type(16))) float f32x16;
typedef __attribute__((ext_vector_type(4))) unsigned int u32x4;
typedef __attribute__((ext_vector_type(2))) unsigned int u32x2;
typedef __attribute__((ext_vector_type(4))) unsigned short u16x4;

static __device__ __forceinline__ u16 f2bf(float f) {
  union { float f; unsigned int u; } a; a.f = f;
  unsigned int u = a.u;
  unsigned int r = (u + 0x7FFFu + ((u >> 16) & 1u)) >> 16;   // RNE
  return (u16)r;
}

#if defined(__has_builtin)
#if __has_builtin(__builtin_amdgcn_exp2f)
#define EXP2F(x) __builtin_amdgcn_exp2f(x)
#endif
#endif
#ifndef EXP2F
#define EXP2F(x) exp2f(x)
#endif

// fast erf-based gelu: Abramowitz-Stegun 7.1.26, |err(erf)| < 2e-7 (vs bf16 ulp ~4e-3)
static __device__ __forceinline__ float gelu_f(float v) {
  float x = fabsf(v) * 0.70710678118654752f;
  float t = __builtin_amdgcn_rcpf(1.0f + 0.3275911f * x);
  float p = t * (0.254829592f + t * (-0.284496736f + t * (1.421413741f +
            t * (-1.453152027f + t * 1.061405429f))));
  float e = EXP2F(-1.4426950408889634f * x * x);
  float er = 1.0f - p * e;                    // erf(|x|)
  er = (v < 0.0f) ? -er : er;
  return 0.5f * v * (1.0f + er);
}

// pack two fp32 -> adjacent bf16 pair (low = a), TRUNCATING (1 v_perm).
static __device__ __forceinline__ unsigned int pkbf_t(float a, float b) {
  unsigned int ua = __builtin_bit_cast(unsigned int, a);
  unsigned int ub = __builtin_bit_cast(unsigned int, b);
  return __builtin_amdgcn_perm(ub, ua, 0x07060302u);  // [ua.hi16 low, ub.hi16 high]
}

// gfx950 cross-lane half-swap: new_a.hi(lanes>=32) = old_b.lo values; new_b.lo = old_a.hi.
static __device__ __forceinline__ void pl32swap(unsigned int &a, unsigned int &b) {
  asm volatile("v_permlane32_swap_b32 %0, %1" : "+v"(a), "+v"(b));
}

static __device__ __forceinline__ void gld_lds16(const u16* g, u16* l) {
  __builtin_amdgcn_global_load_lds((__attribute__((address_space(1))) void*)g,
                                   (__attribute__((address_space(3))) void*)l, 16, 0, 0);
}

#define WAITV(N) asm volatile("s_waitcnt vmcnt(" #N ")" ::: "memory")

// ---------------- router: logits = x @ w_router, accumulate sum(logits^2) ----------------
__global__ void __launch_bounds__(256) router_kernel(const float* __restrict__ x,
    const float* __restrict__ wr, float* __restrict__ logits, float* __restrict__ auxacc)
{
  int tid = threadIdx.x; int lane = tid & 63, wave = tid >> 6;
  int row = blockIdx.x * 4 + wave;                 // 0 .. B*T-1
  const float* xr = x + (size_t)row * D_;
  float dot = 0.f;
#pragma unroll
  for (int j = 0; j < 4; j++) {
    int c = j * 256 + lane * 4;
    f32x4 xv = *(const f32x4*)(xr + c);
    f32x4 wv = *(const f32x4*)(wr + c);
    dot += xv[0]*wv[0] + xv[1]*wv[1] + xv[2]*wv[2] + xv[3]*wv[3];
  }
#pragma unroll
  for (int d = 1; d < 64; d <<= 1) dot += __shfl_xor(dot, d);
  __shared__ float red[4];
  if (lane == 0) { logits[row] = dot; red[wave] = dot; }
  __syncthreads();
  if (tid == 0) {
    float a = red[0]*red[0] + red[1]*red[1] + red[2]*red[2] + red[3]*red[3];
    atomicAdd(auxacc, a);
  }
}

// -------- partial rank: grid (T/256, B, 16 chunks); atomicAdd partial counts into rnk ------
__global__ void __launch_bounds__(256) rankp_kernel(const float* __restrict__ logits,
    int* __restrict__ rnk)
{
  __shared__ float ll[256];
  const int b = blockIdx.y, ch = blockIdx.z;
  const int tid = threadIdx.x;
  const float* lg = logits + (size_t)b * T_;
  const int j0 = ch * 256;
  ll[tid] = lg[j0 + tid];
  __syncthreads();
  const int t = blockIdx.x * 256 + tid;
  const float my = lg[t];
  int rank = 0;
#pragma unroll 4
  for (int j = 0; j < 256; j += 4) {
    f32x4 lj = *(const f32x4*)&ll[j];
    int jg = j0 + j;
    rank += (lj[0] > my) || (lj[0] == my && (jg+0) < t);
    rank += (lj[1] > my) || (lj[1] == my && (jg+1) < t);
    rank += (lj[2] > my) || (lj[2] == my && (jg+2) < t);
    rank += (lj[3] > my) || (lj[3] == my && (jg+3) < t);
  }
  atomicAdd(&rnk[(size_t)b * T_ + t], rank);
}

// ---------------- fused: pass-through unselected OR gather+LN selected; builds idx --------
__global__ void __launch_bounds__(256) lnpass_kernel(const float* __restrict__ x,
    const int* __restrict__ rnk, const float* __restrict__ g, const float* __restrict__ bb,
    float* __restrict__ xs_out, u16* __restrict__ hout, float* __restrict__ out,
    int* __restrict__ idx, const float* __restrict__ acc, float* __restrict__ auxout)
{
  int row = blockIdx.x;            // 0 .. B*T-1
  int tid = threadIdx.x;
  if (row == 0 && tid == 0) auxout[0] = acc[0] * (0.01f / (float)(B_ * T_));
  const float* srow = x + (size_t)row * D_;
  f32x4 v = *(const f32x4*)(srow + tid * 4);
  int r = rnk[row];                // block-uniform
  if (r >= KTOK) {                 // unselected: copy x row to out
    *(f32x4*)(out + (size_t)row * D_ + tid * 4) = v;
    return;
  }
  if (tid == 0) idx[(row >> 12) * KTOK + r] = row & (T_ - 1);   // T_=4096
  size_t mrow = (size_t)(row >> 12) * KTOK + r;
  float s  = v[0] + v[1] + v[2] + v[3];
  float sq = v[0]*v[0] + v[1]*v[1] + v[2]*v[2] + v[3]*v[3];
#pragma unroll
  for (int d = 1; d < 64; d <<= 1) { s += __shfl_xor(s, d); sq += __shfl_xor(sq, d); }
  __shared__ float rs[4], rq[4];
  int lane = tid & 63, wave = tid >> 6;
  if (lane == 0) { rs[wave] = s; rq[wave] = sq; }
  __syncthreads();
  s  = rs[0] + rs[1] + rs[2] + rs[3];
  sq = rq[0] + rq[1] + rq[2] + rq[3];
  float mean = s * (1.0f / D_);
  float var  = sq * (1.0f / D_) - mean * mean;
  float rstd = rsqrtf(var + 1e-5f);
  f32x4 gg = *(const f32x4*)(g + tid * 4);
  f32x4 bv = *(const f32x4*)(bb + tid * 4);
  *(f32x4*)(xs_out + mrow * D_ + tid * 4) = v;
  u16x4 o;
#pragma unroll
  for (int j = 0; j < 4; j++) o[j] = f2bf((v[j] - mean) * rstd * gg[j] + bv[j]);
  *(u16x4*)(hout + mrow * D_ + tid * 4) = o;
}

// ---------------- LayerNorm (no gather) ----------------
__global__ void __launch_bounds__(256) ln2_kernel(const float* __restrict__ src,
    const float* __restrict__ g, const float* __restrict__ bb, u16* __restrict__ hout)
{
  int row = blockIdx.x;
  int tid = threadIdx.x;
  const float* srow = src + (size_t)row * D_;
  f32x4 v = *(const f32x4*)(srow + tid * 4);
  float s  = v[0] + v[1] + v[2] + v[3];
  float sq = v[0]*v[0] + v[1]*v[1] + v[2]*v[2] + v[3]*v[3];
#pragma unroll
  for (int d = 1; d < 64; d <<= 1) { s += __shfl_xor(s, d); sq += __shfl_xor(sq, d); }
  __shared__ float rs[4], rq[4];
  int lane = tid & 63, wave = tid >> 6;
  if (lane == 0) { rs[wave] = s; rq[wave] = sq; }
  __syncthreads();
  s  = rs[0] + rs[1] + rs[2] + rs[3];
  sq = rq[0] + rq[1] + rq[2] + rq[3];
  float mean = s * (1.0f / D_);
  float var  = sq * (1.0f / D_) - mean * mean;
  float rstd = rsqrtf(var + 1e-5f);
  f32x4 gg = *(const f32x4*)(g + tid * 4);
  f32x4 bv = *(const f32x4*)(bb + tid * 4);
  u16x4 o;
#pragma unroll
  for (int j = 0; j < 4; j++) o[j] = f2bf((v[j] - mean) * rstd * gg[j] + bv[j]);
  *(u16x4*)(hout + (size_t)row * D_ + tid * 4) = o;
}

// ---------------- fp32 -> bf16 convert, all 4 weight matrices in one dispatch ----------------
__global__ void __launch_bounds__(256) f2bf_all(const float* __restrict__ s0, const float* __restrict__ s1,
    const float* __restrict__ s2, const float* __restrict__ s3,
    u16* __restrict__ d0, u16* __restrict__ d1, u16* __restrict__ d2, u16* __restrict__ d3)
{
  const size_t c0 = (size_t)3 * D_ * D_, c1 = (size_t)4 * D_ * D_, c2 = (size_t)8 * D_ * D_;
  size_t e = (size_t)blockIdx.x * 1024 + (size_t)threadIdx.x * 4;
  const float* s; u16* d; size_t off;
  if (e < c0)      { s = s0; d = d0; off = e; }
  else if (e < c1) { s = s1; d = d1; off = e - c0; }
  else if (e < c2) { s = s2; d = d2; off = e - c1; }
  else             { s = s3; d = d3; off = e - c2; }
  f32x4 v = *(const f32x4*)(s + off);
  u16x4 o; o[0]=f2bf(v[0]); o[1]=f2bf(v[1]); o[2]=f2bf(v[2]); o[3]=f2bf(v[3]);
  *(u16x4*)(d + off) = o;
}

// ========== GEMM 128x128, BK=64, 4 row-waves, deep-prefetch schedule ===========
// AHM: A is head-major [b][h=ktile][q][64] (attn obuf layout); BK=64==DH so one k-tile is
// exactly one head: row stride 64, k-tile stride KTOK*64. LDS side & math identical.
template<int EPI, bool AHM = false>
__global__ void __launch_bounds__(256, 2) gemm_bt(
    const u16* __restrict__ A, const u16* __restrict__ W,
    const float* __restrict__ bias, float* __restrict__ xs,
    u16* __restrict__ Cb, float* __restrict__ outf,
    const int* __restrict__ idx, u16* __restrict__ vtb, int M, int N, int K)
{
  __shared__ u16 As[2][128 * 64];
  __shared__ u16 Ws[2][128 * 64];
  const int tid = threadIdx.x;
  const int lane = tid & 63, wave = tid >> 6;
  const int m16 = lane & 15, quad = (lane >> 4) & 3;

  // chunked bijective XCD swizzle (grid divisible by 8)
  const int gx = gridDim.x;
  const int id = blockIdx.y * gx + blockIdx.x;
  const int cpx = (gx * (int)gridDim.y) >> 3;
  const int tl = (id & 7) * cpx + (id >> 3);
  const int bx = tl % gx, by = tl / gx;

  const size_t arow0 = (size_t)by * 128;
  const size_t wrow0 = (size_t)bx * 128;

  // stage one [64][64] u16 piece (8KB = 512 chunks), thread t -> chunks t, 256+t
  const int trow = tid >> 3;                // 0..31
  const int tcc  = (tid ^ trow) & 7;        // swizzled source col-chunk (inverse of read XOR)
  auto stagepc = [&](const u16* g0, size_t rs, u16* l0) {
    gld_lds16(g0 + (size_t)trow * rs + tcc * 8,        l0 + (size_t)(tid & ~63) * 8);
    gld_lds16(g0 + (size_t)(32 + trow) * rs + tcc * 8, l0 + 2048 + (size_t)(tid & ~63) * 8);
  };
  auto stage_tile = [&](int u, int s) {     // FIFO: Ar0, Ar1, B0, B1
    size_t kn = (size_t)u * 64;
    if (AHM) {
      const u16* Ab = A + (arow0 >> 11) * (size_t)(H_ * KTOK * DH_)
                        + (arow0 & (KTOK - 1)) * DH_ + (size_t)u * (KTOK * DH_);
      stagepc(Ab,            64, &As[s][0]);
      stagepc(Ab + 64 * 64,  64, &As[s][64 * 64]);
    } else {
      stagepc(A + (arow0)      * K + kn, K, &As[s][0]);
      stagepc(A + (arow0 + 64) * K + kn, K, &As[s][64 * 64]);
    }
    stagepc(W + (wrow0)      * K + kn, K, &Ws[s][0]);
    stagepc(W + (wrow0 + 64) * K + kn, K, &Ws[s][64 * 64]);
  };

  auto ldA = [&](short8 (&f)[2][2], const u16* h) {
#pragma unroll
    for (int mt = 0; mt < 2; mt++) {
      int rr = wave * 32 + mt * 16 + m16;
      int sw = rr & 7;
#pragma unroll
      for (int kk = 0; kk < 2; kk++)
        f[mt][kk] = *(const short8*)&h[rr * 64 + (((kk * 4 + quad) ^ sw) * 8)];
    }
  };
  auto ldB = [&](short8 (&f)[4][2], const u16* h, int half) {
#pragma unroll
    for (int nt = 0; nt < 4; nt++) {
      int rb = half * 64 + nt * 16 + m16;
      int sw = rb & 7;
#pragma unroll
      for (int kk = 0; kk < 2; kk++)
        f[nt][kk] = *(const short8*)&h[rb * 64 + (((kk * 4 + quad) ^ sw) * 8)];
    }
  };

  f32x4 acc[2][8];
#pragma unroll
  for (int mt = 0; mt < 2; mt++)
#pragma unroll
    for (int n = 0; n < 8; n++) acc[mt][n] = (f32x4)0.0f;

  stage_tile(0, 0);

  const int NT = K >> 6;
  short8 af[2][2], bf[4][2], bf2[4][2];

  for (int t = 0; t < NT; t++) {
    const int cur = t & 1;
    const bool last = (t == NT - 1);

    WAITV(2);                                  // Ar0,Ar1,B0(t) done (issued full tile ago)
    __builtin_amdgcn_s_barrier();
    __builtin_amdgcn_sched_barrier(0);
    if (!last) stage_tile(t + 1, cur ^ 1);

    // p0: cols 0-63
    ldA(af, &As[cur][0]);
    ldB(bf, &Ws[cur][0], 0);
    __builtin_amdgcn_s_setprio(1);
#pragma unroll
    for (int mt = 0; mt < 2; mt++)
#pragma unroll
      for (int nt = 0; nt < 4; nt++)
#pragma unroll
        for (int kk = 0; kk < 2; kk++)
          acc[mt][nt] = __builtin_amdgcn_mfma_f32_16x16x32_bf16(af[mt][kk], bf[nt][kk], acc[mt][nt], 0, 0, 0);
    __builtin_amdgcn_s_setprio(0);

    if (last) { WAITV(0); } else { WAITV(8); } // B1(t) done; t+1's 8 loads stay in flight
    __builtin_amdgcn_s_barrier();
    __builtin_amdgcn_sched_barrier(0);

    // p1: cols 64-127 (barrier-free drift region)
    ldB(bf2, &Ws[cur][0], 1);
    __builtin_amdgcn_s_setprio(1);
#pragma unroll
    for (int mt = 0; mt < 2; mt++)
#pragma unroll
      for (int nt = 0; nt < 4; nt++)
#pragma unroll
        for (int kk = 0; kk < 2; kk++)
          acc[mt][4 + nt] = __builtin_amdgcn_mfma_f32_16x16x32_bf16(af[mt][kk], bf2[nt][kk], acc[mt][4 + nt], 0, 0, 0);
    __builtin_amdgcn_s_setprio(0);
  }

  // ---- epilogue ----
#pragma unroll
  for (int half = 0; half < 2; half++) {
#pragma unroll
    for (int mt = 0; mt < 2; mt++) {
#pragma unroll
      for (int nt = 0; nt < 4; nt++) {
        f32x4 a = acc[mt][half * 4 + nt];
        size_t col = wrow0 + half * 64 + nt * 16 + m16;
        float bvv = bias[col];
        size_t rowb = arow0 + wave * 32 + mt * 16 + quad * 4;
        if (EPI == 0) {
          if ((int)col < 2 * D_) {
            float sc = ((int)col < D_) ? 0.18033688f : 1.0f;  // fold 1/sqrt(dh)*log2(e) into Q
#pragma unroll
            for (int r = 0; r < 4; r++)
              Cb[(rowb + r) * (size_t)N + col] = f2bf((a[r] + bvv) * sc);
          } else {
            int hdh = (int)col - 2 * D_;
            int bb2 = (int)(rowb >> 11);
            int tok = (int)(rowb & (KTOK - 1));
            u16x4 o;
#pragma unroll
            for (int r = 0; r < 4; r++) o[r] = f2bf(a[r] + bvv);
            *(u16x4*)&vtb[(((size_t)(bb2 * H_) + (hdh >> 6)) * 64 + (hdh & 63)) * KTOK + tok] = o;
          }
        } else if (EPI == 1) {
#pragma unroll
          for (int r = 0; r < 4; r++) {
            size_t o = (rowb + r) * (size_t)N + col;
            xs[o] = xs[o] + (a[r] + bvv);
          }
        } else {
#pragma unroll
          for (int r = 0; r < 4; r++) {
            size_t row = rowb + r;
            int b = (int)(row >> 11);
            int i = (int)(row & (KTOK - 1));
            int t = idx[b * KTOK + i];
            float vv = xs[row * (size_t)D_ + col] + (a[r] + bvv);
            outf[((size_t)b * T_ + t) * D_ + col] = vv;
          }
        }
      }
    }
  }
}

// ================= FF1 GEMM: 256x256, BK=64, 512 threads, deep-prefetch schedule ===========
__global__ void __launch_bounds__(512, 1) gemm_ff1(
    const u16* __restrict__ A, const u16* __restrict__ W,
    const float* __restrict__ bias, u16* __restrict__ Cb, int M, int N, int K)
{
  __shared__ u16 Asm[2][2][128 * 64];
  __shared__ u16 Bsm[2][2][128 * 64];

  const int tid = threadIdx.x;
  const int lane = tid & 63;
  const int w = tid >> 6;                  // wave 0..7
  const int m16 = lane & 15, quad = (lane >> 4) & 3;
  const int rowA = (w >> 2) * 64;          // within A-half
  const int rowB = (w & 3) * 32;           // within B-half

  const int gx = gridDim.x;
  const int id = blockIdx.y * gx + blockIdx.x;
  const int cpx = (gx * (int)gridDim.y) >> 3;
  const int tl = (id & 7) * cpx + (id >> 3);
  const int bx = tl % gx, by = tl / gx;

  const int arow0 = by * 256;
  const int wcol0 = bx * 256;

  const int th8 = tid >> 3;
  const int ccs = (tid ^ th8) & 7;
  auto stage = [&](const u16* g0, u16* l0) {       // one 128x64 half-tile (16KB), 2 loads/thread
    gld_lds16(g0 + (size_t)th8 * K + ccs * 8,        l0 + (size_t)(tid & ~63) * 8);
    gld_lds16(g0 + (size_t)(64 + th8) * K + ccs * 8, l0 + 4096 + (size_t)(tid & ~63) * 8);
  };
  auto stage_tile = [&](int u, int s) {            // FIFO order: A0, B0, A1, B1
    size_t kn = (size_t)u * 64;
    stage(A + (size_t)arow0 * K + kn,         &Asm[s][0][0]);
    stage(W + (size_t)wcol0 * K + kn,         &Bsm[s][0][0]);
    stage(A + (size_t)(arow0 + 128) * K + kn, &Asm[s][1][0]);
    stage(W + (size_t)(wcol0 + 128) * K + kn, &Bsm[s][1][0]);
  };

  auto ldA = [&](short8 (&f)[4][2], const u16* h) {
#pragma unroll
    for (int mt = 0; mt < 4; mt++) {
      int rr = rowA + mt * 16 + m16;
      int sw = rr & 7;
#pragma unroll
      for (int kk = 0; kk < 2; kk++)
        f[mt][kk] = *(const short8*)&h[rr * 64 + (((kk * 4 + quad) ^ sw) * 8)];
    }
  };
  auto ldB = [&](short8 (&f)[2][2], const u16* h) {
#pragma unroll
    for (int nt = 0; nt < 2; nt++) {
      int rb = rowB + nt * 16 + m16;
      int sw = rb & 7;
#pragma unroll
      for (int kk = 0; kk < 2; kk++)
        f[nt][kk] = *(const short8*)&h[rb * 64 + (((kk * 4 + quad) ^ sw) * 8)];
    }
  };

  f32x4 acc[4][4][2];
#pragma unroll
  for (int q = 0; q < 4; q++)
#pragma unroll
    for (int mt = 0; mt < 4; mt++)
#pragma unroll
      for (int nt = 0; nt < 2; nt++) acc[q][mt][nt] = (f32x4)0.0f;

#define MMQ(QD, FA, FB) do { \
  __builtin_amdgcn_s_setprio(1); \
  _Pragma("unroll") for (int mt = 0; mt < 4; mt++) \
  _Pragma("unroll") for (int nt = 0; nt < 2; nt++) \
  _Pragma("unroll") for (int kk = 0; kk < 2; kk++) \
    acc[QD][mt][nt] = __builtin_amdgcn_mfma_f32_16x16x32_bf16(FA[mt][kk], FB[nt][kk], acc[QD][mt][nt], 0, 0, 0); \
  __builtin_amdgcn_s_setprio(0); } while (0)

  stage_tile(0, 0);

  const int NT = K >> 6;
  short8 af[4][2], af2[4][2], bf[2][2], bf2[2][2];

  for (int t = 0; t < NT; t++) {
    const int cur = t & 1;
    const bool last = (t == NT - 1);

    WAITV(4);                                   // A0,B0(t) done; A1,B1(t) may be in flight
    __builtin_amdgcn_s_barrier();
    __builtin_amdgcn_sched_barrier(0);
    if (!last) stage_tile(t + 1, cur ^ 1);      // 8 loads; slots freed by this barrier

    // p0: (A0,B0)
    ldA(af, &Asm[cur][0][0]);
    ldB(bf, &Bsm[cur][0][0]);
    MMQ(0, af, bf);

    if (last) { WAITV(0); } else { WAITV(8); }  // A1,B1(t) done; t+1's 8 loads in flight
    __builtin_amdgcn_s_barrier();
    __builtin_amdgcn_sched_barrier(0);

    // p1..p3: barrier-free drift region
    ldB(bf2, &Bsm[cur][1][0]);
    MMQ(1, af, bf2);
    ldA(af2, &Asm[cur][1][0]);
    MMQ(2, af2, bf);
    MMQ(3, af2, bf2);
  }
#undef MMQ

  // ---- epilogue: gelu(bf16) ----
#pragma unroll
  for (int qd = 0; qd < 4; qd++) {
    const int ha = qd >> 1, hb = qd & 1;
#pragma unroll
    for (int mt = 0; mt < 4; mt++) {
#pragma unroll
      for (int nt = 0; nt < 2; nt++) {
        f32x4 a = acc[qd][mt][nt];
        size_t col = (size_t)wcol0 + hb * 128 + (w & 3) * 32 + nt * 16 + m16;
        float bvv = bias[col];
        size_t rowb = (size_t)arow0 + ha * 128 + (w >> 2) * 64 + mt * 16 + quad * 4;
#pragma unroll
        for (int r = 0; r < 4; r++)
          Cb[(rowb + r) * (size_t)N + col] = f2bf(gelu_f(a[r] + bvv));
      }
    }
  }
}

// ---------------- flash attention v9: 32x32 MFMA, P stays IN REGISTERS -------------------
// S^T via mfma_32x32x16(A=K[key][dh], B=Q[dh][q]): D[key][q], lane holds col q=lane&31 and
// 16 key-rows. That q is EXACTLY the PV A-operand row index -> no LDS round-trip for P; the
// key-slice split across lane-32 halves is fixed by v_permlane32_swap_b32 (pure VALU):
// per tile: 16 cvt-pack + 8 swaps replace 12 conflicted LDS ops (the 4.19M conflict cycles).
// Ps LDS (32KB) deleted -> 48KB total. l via mfma(P, ones): lacc reg-layout == oacc rows.
// Triple-buffer K/V, depth-2 prefetch, counted waits (round-8 schedule).
__global__ void __launch_bounds__(512, 2) attn_kernel(const u16* __restrict__ qkv,
                                                      const u16* __restrict__ vtb,
                                                      u16* __restrict__ obuf)
{
  __shared__ u16 Ks[3][64 * 64];        // [key][dh], 24 KB
  __shared__ u16 Vs[3][64 * 64];        // [dh][key], 24 KB   total 48 KB

  const int tid = threadIdx.x;
  const int lane = tid & 63, wave = tid >> 6;     // wave 0..7
  const int l31 = lane & 31, hi = lane >> 5;
  const int bh = blockIdx.x;                      // XCD = bh&7
  const int b = bh >> 4, h = bh & 15;
  const int q0 = blockIdx.y * 256 + wave * 32;    // this wave: q0..q0+31

  const u16* base = qkv + ((size_t)b * KTOK) * (3 * D_) + h * DH_;
  const u16* vb   = vtb + (size_t)bh * 64 * KTOK; // rows = dh, stride KTOK

  // Q B-frags (loaded once): B[k=dh][n=q]: n=lane&31=q, k=(lane>>5)*8+i per 16-dh step
  short8 qf[4];
  {
    const u16* qrow = base + (size_t)(q0 + l31) * (3 * D_);
#pragma unroll
    for (int ks = 0; ks < 4; ks++)
      qf[ks] = *(const short8*)(qrow + ks * 16 + hi * 8);
  }
  short8 vone;                         // bf16 1.0 broadcast (B-operand for l = P @ ones)
#pragma unroll
  for (int i = 0; i < 8; i++) vone[i] = (short)0x3F80;

  f32x16 oacc[2];
  oacc[0] = (f32x16)0.0f; oacc[1] = (f32x16)0.0f;
  f32x16 lacc = (f32x16)0.0f;

  // stage one 64x64 u16 tile: 512 chunks of 16B, one gld_lds per thread (K and V)
  auto stage_kv = [&](int u, int s) {
    int key = tid >> 3;
    int cc = (tid ^ key) & 7;
    gld_lds16(base + (size_t)(u * 64 + key) * (3 * D_) + D_ + cc * 8,
              &Ks[s][0] + (size_t)(tid & ~63) * 8);
    gld_lds16(vb + (u * 64) + (size_t)key * KTOK + cc * 8,
              &Vs[s][0] + (size_t)(tid & ~63) * 8);
  };

  const int NT = KTOK / 64;                      // 32
  stage_kv(0, 0);
  stage_kv(1, 1);
  WAITV(2);                                      // tile 0 ready; tile 1 in flight
  __builtin_amdgcn_s_barrier();
  __builtin_amdgcn_sched_barrier(0);

  int buf = 0;
  for (int t = 0; t < NT; t++) {
    if (t + 2 < NT) {
      int s2 = buf + 2; if (s2 >= 3) s2 -= 3;
      stage_kv(t + 2, s2);                       // lands 2 tiles ahead of use
    }
    const u16* Kb = &Ks[buf][0];
    const u16* Vb = &Vs[buf][0];

    // ---- per 32-key group: S^T = K Q^T, exp2, pack, permlane-swap ----
    unsigned int w[2][8];
#pragma unroll
    for (int kg = 0; kg < 2; kg++) {
      f32x16 sacc = (f32x16)0.0f;
      __builtin_amdgcn_s_setprio(1);
#pragma unroll
      for (int ks = 0; ks < 4; ks++) {
        int row = kg * 32 + l31;
        int c = (ks * 2 + hi) ^ (row & 7);
        short8 kf = *(const short8*)&Kb[row * 64 + c * 8];
        sacc = __builtin_amdgcn_mfma_f32_32x32x16_bf16(kf, qf[ks], sacc, 0, 0, 0);
      }
      __builtin_amdgcn_s_setprio(0);
#pragma unroll
      for (int i = 0; i < 8; i++) {
        float p0 = EXP2F(sacc[2 * i]);
        float p1 = EXP2F(sacc[2 * i + 1]);
        w[kg][i] = pkbf_t(p0, p1);
      }
      // redistribute key-slices across lane-32 halves: (dw0,dw2) and (dw1,dw3) per k-step
      pl32swap(w[kg][0], w[kg][2]); pl32swap(w[kg][1], w[kg][3]);
      pl32swap(w[kg][4], w[kg][6]); pl32swap(w[kg][5], w[kg][7]);
    }
    // P A-frags: pa[j] (j = kg*2+kk, keys j*16..+16) = post-swap w[kg][kk*4..+4]
    short8 pa[4];
#pragma unroll
    for (int kg = 0; kg < 2; kg++)
#pragma unroll
      for (int kk = 0; kk < 2; kk++) {
        u32x4 d; d[0] = w[kg][kk*4]; d[1] = w[kg][kk*4+1]; d[2] = w[kg][kk*4+2]; d[3] = w[kg][kk*4+3];
        pa[kg * 2 + kk] = __builtin_bit_cast(short8, d);
      }

    // ---- PV + l: O[q][dh] += P[q][key] V[key][dh] ----
    __builtin_amdgcn_s_setprio(1);
#pragma unroll
    for (int dg = 0; dg < 2; dg++) {
#pragma unroll
      for (int j = 0; j < 4; j++) {
        int row = dg * 32 + l31;                 // dh row in Vs
        int c = (j * 2 + hi) ^ (row & 7);        // key chunk j*2+hi
        short8 vf = *(const short8*)&Vb[row * 64 + c * 8];
        oacc[dg] = __builtin_amdgcn_mfma_f32_32x32x16_bf16(pa[j], vf, oacc[dg], 0, 0, 0);
      }
    }
#pragma unroll
    for (int j = 0; j < 4; j++)
      lacc = __builtin_amdgcn_mfma_f32_32x32x16_bf16(pa[j], vone, lacc, 0, 0, 0);
    __builtin_amdgcn_s_setprio(0);

    if (t < NT - 1) {
      if (t < NT - 2) { WAITV(2); } else { WAITV(0); }   // t+1 ready; t+2 stays in flight
      __builtin_amdgcn_s_barrier();
      __builtin_amdgcn_sched_barrier(0);
    }
    buf = (buf == 2) ? 0 : buf + 1;
  }

  // ---- epilogue: D rows (r&3)+8*(r>>2)+4*hi, cols dh = dg*32 + l31; lacc[r] = l[row] ----
#pragma unroll
  for (int r = 0; r < 16; r++) {
    float rl = 1.0f / lacc[r];
    int qq = q0 + (r & 3) + 8 * (r >> 2) + 4 * hi;
#pragma unroll
    for (int dg = 0; dg < 2; dg++)
      obuf[((size_t)bh * KTOK + qq) * DH_ + dg * 32 + l31] = f2bf(oacc[dg][r] * rl);
  }
}

// ---------------- launch ----------------
extern "C" void kernel_launch(void* const* d_in, const int* in_sizes, int n_in,
                              void* d_out, int out_size, void* d_ws, size_t ws_size,
                              hipStream_t stream)
{
  (void)in_sizes; (void)n_in; (void)out_size; (void)ws_size;
  const float* x          = (const float*)d_in[0];
  const float* w_router   = (const float*)d_in[1];
  const float* in_proj_w  = (const float*)d_in[2];
  const float* in_proj_b  = (const float*)d_in[3];
  const float* out_proj_w = (const float*)d_in[4];
  const float* out_proj_b = (const float*)d_in[5];
  const float* w1         = (const float*)d_in[6];
  const float* b1         = (const float*)d_in[7];
  const float* w2         = (const float*)d_in[8];
  const float* b2         = (const float*)d_in[9];
  const float* ln1g       = (const float*)d_in[10];
  const float* ln1b       = (const float*)d_in[11];
  const float* ln2g       = (const float*)d_in[12];
  const float* ln2b       = (const float*)d_in[13];
  float* out = (float*)d_out;

  char* w = (char*)d_ws;
  auto alloc = [&](size_t bytes) -> char* {
    char* p = w; w += (bytes + 255) & ~(size_t)255; return p;
  };
  float* logits = (float*)alloc((size_t)B_ * T_ * 4);
  int*   rnk    = (int*)  alloc((size_t)B_ * T_ * 4);
  int*   idx    = (int*)  alloc((size_t)B_ * KTOK * 4);
  float* auxacc = (float*)alloc(256);
  u16* inpw  = (u16*)alloc((size_t)3 * D_ * D_ * 2);
  u16* outpw = (u16*)alloc((size_t)D_ * D_ * 2);
  u16* w1b   = (u16*)alloc((size_t)4 * D_ * D_ * 2);
  u16* w2b   = (u16*)alloc((size_t)4 * D_ * D_ * 2);
  float* xs  = (float*)alloc((size_t)MROWS * D_ * 4);
  u16* hbuf  = (u16*)alloc((size_t)MROWS * D_ * 2);
  char* region = alloc((size_t)MROWS * 4 * D_ * 2);      // 64 MB: qkv(48)+obuf(16), reused by ff
  u16* qkvb = (u16*)region;
  u16* obuf = (u16*)(region + (size_t)MROWS * 3 * D_ * 2);
  u16* ffb  = (u16*)region;
  u16* vtb  = (u16*)alloc((size_t)B_ * H_ * DH_ * KTOK * 2);   // 16 MB: V transposed [bh][dh][tok]

  (void)hipMemsetAsync(auxacc, 0, 4, stream);
  (void)hipMemsetAsync(rnk, 0, (size_t)B_ * T_ * 4, stream);

  router_kernel<<<B_ * T_ / 4, 256, 0, stream>>>(x, w_router, logits, auxacc);
  rankp_kernel<<<dim3(T_ / 256, B_, 16), 256, 0, stream>>>(logits, rnk);
  lnpass_kernel<<<B_ * T_, 256, 0, stream>>>(x, rnk, ln1g, ln1b, xs, hbuf, out,
                                             idx, auxacc, out + (size_t)B_ * T_ * D_);

  f2bf_all<<<12 * D_ * D_ / 1024, 256, 0, stream>>>(in_proj_w, out_proj_w, w1, w2,
                                                    inpw, outpw, w1b, w2b);

  gemm_bt<0><<<dim3(3 * D_ / 128, MROWS / 128), 256, 0, stream>>>(
      hbuf, inpw, in_proj_b, nullptr, qkvb, nullptr, nullptr, vtb, MROWS, 3 * D_, D_);
  attn_kernel<<<dim3(B_ * H_, KTOK / 256), 512, 0, stream>>>(qkvb, vtb, obuf);
  gemm_bt<1, true><<<dim3(D_ / 128, MROWS / 128), 256, 0, stream>>>(
      obuf, outpw, out_proj_b, xs, nullptr, nullptr, nullptr, nullptr, MROWS, D_, D_);
  ln2_kernel<<<MROWS, 256, 0, stream>>>(xs, ln2g, ln2b, hbuf);
  gemm_ff1<<<dim3(4 * D_ / 256, MROWS / 256), 512, 0, stream>>>(
      hbuf, w1b, b1, ffb, MROWS, 4 * D_, D_);
  gemm_bt<3><<<dim3(D_ / 128, MROWS / 128), 256, 0, stream>>>(
      ffb, w2b, b2, xs, nullptr, out, idx, nullptr, MROWS, D_, 4 * D_);
}